// Round 3
// baseline (2329.425 us; speedup 1.0000x reference)
//
#include <hip/hip_runtime.h>
#include <math.h>

#define B_ 8
#define N_ 512
#define T_ 64
#define NIN_ 64
#define NE_ 128
#define NH_ 128
#define NR_ 4096   // B*N

typedef __attribute__((ext_vector_type(8))) short s8_t;   // 8 bf16 = 16B
typedef __attribute__((ext_vector_type(4))) float f4_t;

__device__ __forceinline__ float sigm(float x) {
  x = fminf(fmaxf(x, -30.f), 30.f);
  return 1.f / (1.f + __expf(-x));
}
__device__ __forceinline__ float tanh_fast(float x) {
  x = fminf(fmaxf(x, -15.f), 15.f);
  float e = __expf(2.f * x);
  return (e - 1.f) / (e + 1.f);
}
__device__ __forceinline__ unsigned short f2b(float f) {
  union { float f; unsigned u; } v; v.f = f;
  unsigned r = (v.u + 0x7FFFu + ((v.u >> 16) & 1u)) >> 16;
  return (unsigned short)r;
}

// ---------------- one-time setup kernels ----------------

__global__ __launch_bounds__(256) void k_dinv(const float* __restrict__ A,
                                              float* __restrict__ dinv) {
  int row = blockIdx.x * 4 + (threadIdx.x >> 6);
  int lane = threadIdx.x & 63;
  const float* a = A + (size_t)row * N_;
  float s = 0.f;
  for (int j = lane; j < N_; j += 64) s += a[j];
  #pragma unroll
  for (int off = 32; off > 0; off >>= 1) s += __shfl_down(s, off);
  if (lane == 0) dinv[row] = (s > 0.f) ? rsqrtf(s) : 0.f;
}

// WC (fp32, [128][512]) = Wpe @ concat(Wx*[128:256,:])
__global__ __launch_bounds__(256) void k_wc(
    const float* __restrict__ Wpe,
    const float* __restrict__ Wii, const float* __restrict__ Wif,
    const float* __restrict__ Wig, const float* __restrict__ Wio,
    float* __restrict__ WC) {
  int idx = blockIdx.x * 256 + threadIdx.x;    // 65536
  int k = idx >> 9, col = idx & 511, g = col >> 7, j = col & 127;
  const float* Wx = (g == 0) ? Wii : (g == 1) ? Wif : (g == 2) ? Wig : Wio;
  float s = 0.f;
  for (int mm = 0; mm < 128; mm++)
    s += Wpe[(size_t)k * 128 + mm] * Wx[(size_t)(128 + mm) * 128 + j];
  WC[idx] = s;
}

// bcat[col] = bx + bh + bpe @ W*[128:256]
__global__ __launch_bounds__(256) void k_bcat(
    const float* __restrict__ bii, const float* __restrict__ bif,
    const float* __restrict__ big, const float* __restrict__ bio,
    const float* __restrict__ bhi, const float* __restrict__ bhf,
    const float* __restrict__ bhg, const float* __restrict__ bho,
    const float* __restrict__ bpe,
    const float* __restrict__ Wii, const float* __restrict__ Wif,
    const float* __restrict__ Wig, const float* __restrict__ Wio,
    float* __restrict__ bcat) {
  int col = blockIdx.x * 256 + threadIdx.x;   // < 512
  int g = col >> 7, j = col & 127;
  const float* bx = (g == 0) ? bii : (g == 1) ? bif : (g == 2) ? big : bio;
  const float* bh = (g == 0) ? bhi : (g == 1) ? bhf : (g == 2) ? bhg : bho;
  const float* Wx = (g == 0) ? Wii : (g == 1) ? Wif : (g == 2) ? Wig : Wio;
  float s = bx[j] + bh[j];
  for (int k = 0; k < NE_; k++) s += bpe[k] * Wx[(size_t)(128 + k) * NH_ + j];
  bcat[col] = s;
}

// WUP2 (bf16 k-packed [(256/8)][512][8]): rows 0:128 = WC, 128:256 = Wh*
__global__ __launch_bounds__(256) void k_pack_wu2(
    const float* __restrict__ WC,
    const float* __restrict__ Whi, const float* __restrict__ Whf,
    const float* __restrict__ Whg, const float* __restrict__ Who,
    unsigned short* __restrict__ WUP2) {
  int idx = blockIdx.x * 256 + threadIdx.x;    // 131072
  int k = idx >> 9, col = idx & 511, g = col >> 7, j = col & 127;
  float v;
  if (k < 128) v = WC[(size_t)k * 512 + col];
  else {
    const float* Wh = (g == 0) ? Whi : (g == 1) ? Whf : (g == 2) ? Whg : Who;
    v = Wh[(size_t)(k - 128) * 128 + j];
  }
  WUP2[((size_t)(k >> 3) * 512 + col) * 8 + (k & 7)] = f2b(v);
}

// WseP [(64/8)][128][8], WxeP [(128/8)][512][8] (es->gate rows 0:128), WoutP [(128/8)][64][8]
__global__ __launch_bounds__(256) void k_pack_misc(
    const float* __restrict__ Wse,
    const float* __restrict__ Wii, const float* __restrict__ Wif,
    const float* __restrict__ Wig, const float* __restrict__ Wio,
    const float* __restrict__ Wout,
    unsigned short* __restrict__ WseP, unsigned short* __restrict__ WxeP,
    unsigned short* __restrict__ WoutP) {
  int idx = blockIdx.x * 256 + threadIdx.x;    // 81920
  if (idx < 8192) {
    int k = idx >> 7, c = idx & 127;
    WseP[((size_t)(k >> 3) * 128 + c) * 8 + (k & 7)] = f2b(Wse[(size_t)k * 128 + c]);
  } else if (idx < 8192 + 65536) {
    int i = idx - 8192;
    int k = i >> 9, col = i & 511, g = col >> 7, j = col & 127;
    const float* Wx = (g == 0) ? Wii : (g == 1) ? Wif : (g == 2) ? Wig : Wio;
    WxeP[((size_t)(k >> 3) * 512 + col) * 8 + (k & 7)] = f2b(Wx[(size_t)k * 128 + j]);
  } else if (idx < 8192 + 65536 + 8192) {
    int i = idx - 8192 - 65536;
    int k = i >> 6, c = i & 63;
    WoutP[((size_t)(k >> 3) * 64 + c) * 8 + (k & 7)] = f2b(Wout[(size_t)k * 64 + c]);
  }
}

// ---------------- persistent fused kernel ----------------
// 256 blocks x 256 threads; block g owns rows r0=16g..16g+15; batch b = g>>5.
// Per-batch producer-consumer sync via monotone counters (agent scope).
__global__ __launch_bounds__(256, 1) void k_persist(
    const float* __restrict__ A, const float* __restrict__ dinv,
    const float* __restrict__ X,
    const unsigned short* __restrict__ WseP, const float* __restrict__ bse,
    const unsigned short* __restrict__ WxeP, const float* __restrict__ bcat,
    const unsigned short* __restrict__ WUP2,
    const unsigned short* __restrict__ WoutP, const float* __restrict__ bout,
    unsigned short* __restrict__ hP,   // [2][8][64*128*8]
    int* __restrict__ cnt,             // [8*16]
    float* __restrict__ out) {
  __shared__ __align__(16) unsigned short as[16][520];   // scaled A rows, bf16
  __shared__ __align__(16) unsigned short xh[16][264];   // [G | h_own] bf16
  __shared__ __align__(16) float zb[4][16][132];         // gate exchange

  const int t = threadIdx.x;
  const int g = blockIdx.x;
  const int r0 = g * 16;
  const int b = g >> 5;
  const int l = t & 63, w = t >> 6, m = l & 15, kg = l >> 4;

  float* X0s = &zb[0][0][0];   // 1024 floats (prologue only)
  float* dvb = X0s + 1024;     // 512 floats (prologue only)

  // ---- prologue: stage inputs, compute espre into registers ----
  for (int i = t; i < 512; i += 256) dvb[i] = dinv[b * 512 + i];
  for (int i = t; i < 1024; i += 256) {
    int r = i >> 6, c = i & 63;
    float v = X[((size_t)(r0 + r) * T_) * NIN_ + c];
    X0s[i] = v;
    out[((size_t)(r0 + r) * T_) * NIN_ + c] = v;   // out[:, t=0] = X0
  }
  __syncthreads();
  for (int i = t; i < 1024; i += 256) xh[i >> 6][i & 63] = f2b(X0s[i]);
  for (int i = t; i < 8192; i += 256) {
    int r = i >> 9, k = i & 511;
    as[r][k] = f2b(A[(size_t)(r0 + r) * 512 + k] * dinv[r0 + r] * dvb[k]);
  }
  __syncthreads();
  // es = X0 @ WseP + bse -> bf16 -> xh[:,128:256]
  {
    f4_t e[2];
    #pragma unroll
    for (int nt = 0; nt < 2; nt++) {
      float bv = bse[w * 32 + nt * 16 + m];
      #pragma unroll
      for (int r = 0; r < 4; r++) e[nt][r] = bv;
    }
    for (int kc = 0; kc < 2; kc++) {
      s8_t a = *(const s8_t*)&xh[m][kc * 32 + kg * 8];
      #pragma unroll
      for (int nt = 0; nt < 2; nt++) {
        s8_t bf = *(const s8_t*)&WseP[((size_t)(kc * 4 + kg) * 128 + w * 32 + nt * 16 + m) * 8];
        e[nt] = __builtin_amdgcn_mfma_f32_16x16x32_bf16(a, bf, e[nt], 0, 0, 0);
      }
    }
    #pragma unroll
    for (int nt = 0; nt < 2; nt++)
      #pragma unroll
      for (int r = 0; r < 4; r++)
        xh[kg * 4 + r][128 + w * 32 + nt * 16 + m] = f2b(e[nt][r]);
  }
  __syncthreads();
  // espre (Z-GEMM acc init) in registers: esr = es @ WxeP + bcat (C-layout)
  f4_t esr[8];
  #pragma unroll
  for (int nt = 0; nt < 8; nt++) {
    float bv = bcat[w * 128 + nt * 16 + m];
    #pragma unroll
    for (int r = 0; r < 4; r++) esr[nt][r] = bv;
  }
  for (int kc = 0; kc < 4; kc++) {
    s8_t a = *(const s8_t*)&xh[m][128 + kc * 32 + kg * 8];
    #pragma unroll
    for (int nt = 0; nt < 8; nt++) {
      s8_t bf = *(const s8_t*)&WxeP[((size_t)(kc * 4 + kg) * 512 + w * 128 + nt * 16 + m) * 8];
      esr[nt] = __builtin_amdgcn_mfma_f32_16x16x32_bf16(a, bf, esr[nt], 0, 0, 0);
    }
  }
  // persistent per-thread state
  f4_t oacc;
  #pragma unroll
  for (int r = 0; r < 4; r++) oacc[r] = X0s[(kg * 4 + r) * 64 + w * 16 + m];
  const float bo = bout[w * 16 + m];
  float cs[8];
  #pragma unroll
  for (int q = 0; q < 8; q++) cs[q] = 0.f;
  __syncthreads();
  for (int i = t; i < 16 * 264; i += 256) ((unsigned short*)xh)[i] = 0;
  __syncthreads();

  // ---- main loop over timesteps ----
  for (int tt = 1; tt < T_; tt++) {
    if (tt > 1) {
      // wait for all 32 blocks of this batch to publish h^{tt-1}
      if (t == 0) {
        const int need = 32 * (tt - 1);
        while (__hip_atomic_load(cnt + b * 16, __ATOMIC_ACQUIRE,
                                 __HIP_MEMORY_SCOPE_AGENT) < need)
          __builtin_amdgcn_s_sleep(4);
      }
      __syncthreads();
      // graph GEMM: G(own rows) = as @ h_batch ; scatter bf16 -> xh[:,0:128]
      const unsigned short* hPb =
          hP + ((size_t)((tt - 1) & 1) * 8 + b) * 65536;
      f4_t gacc[2];
      #pragma unroll
      for (int nt = 0; nt < 2; nt++)
        #pragma unroll
        for (int r = 0; r < 4; r++) gacc[nt][r] = 0.f;
      for (int kc = 0; kc < 16; kc++) {
        s8_t a = *(const s8_t*)&as[m][kc * 32 + kg * 8];
        #pragma unroll
        for (int nt = 0; nt < 2; nt++) {
          s8_t bf = *(const s8_t*)&hPb[((size_t)(kc * 4 + kg) * 128 + w * 32 + nt * 16 + m) * 8];
          gacc[nt] = __builtin_amdgcn_mfma_f32_16x16x32_bf16(a, bf, gacc[nt], 0, 0, 0);
        }
      }
      #pragma unroll
      for (int nt = 0; nt < 2; nt++)
        #pragma unroll
        for (int r = 0; r < 4; r++)
          xh[kg * 4 + r][w * 32 + nt * 16 + m] = f2b(gacc[nt][r]);
      __syncthreads();
    }
    // Z-GEMM: acc = espre + [G|h] @ WUP2
    f4_t acc[8];
    #pragma unroll
    for (int nt = 0; nt < 8; nt++) acc[nt] = esr[nt];
    for (int kc = 0; kc < 8; kc++) {
      s8_t a = *(const s8_t*)&xh[m][kc * 32 + kg * 8];
      #pragma unroll
      for (int nt = 0; nt < 8; nt++) {
        s8_t bf = *(const s8_t*)&WUP2[((size_t)(kc * 4 + kg) * 512 + w * 128 + nt * 16 + m) * 8];
        acc[nt] = __builtin_amdgcn_mfma_f32_16x16x32_bf16(a, bf, acc[nt], 0, 0, 0);
      }
    }
    #pragma unroll
    for (int nt = 0; nt < 8; nt++)
      #pragma unroll
      for (int r = 0; r < 4; r++)
        zb[w][kg * 4 + r][nt * 16 + m] = acc[nt][r];
    __syncthreads();
    // cell update: thread owns (row = t>>4, cols (t&15)*8..+7); c-state in regs
    {
      const int row = t >> 4, cg = t & 15;
      float zi[8], zf[8], zg[8], zo[8];
      *(f4_t*)&zi[0] = *(f4_t*)&zb[0][row][cg * 8];
      *(f4_t*)&zi[4] = *(f4_t*)&zb[0][row][cg * 8 + 4];
      *(f4_t*)&zf[0] = *(f4_t*)&zb[1][row][cg * 8];
      *(f4_t*)&zf[4] = *(f4_t*)&zb[1][row][cg * 8 + 4];
      *(f4_t*)&zg[0] = *(f4_t*)&zb[2][row][cg * 8];
      *(f4_t*)&zg[4] = *(f4_t*)&zb[2][row][cg * 8 + 4];
      *(f4_t*)&zo[0] = *(f4_t*)&zb[3][row][cg * 8];
      *(f4_t*)&zo[4] = *(f4_t*)&zb[3][row][cg * 8 + 4];
      s8_t hv8;
      unsigned short hbits[8];
      #pragma unroll
      for (int q = 0; q < 8; q++) {
        float it = sigm(zi[q]), ft = sigm(zf[q]);
        float gt = tanh_fast(zg[q]), ot = sigm(zo[q]);
        cs[q] = ft * cs[q] + it * gt;
        float hvq = ot * tanh_fast(cs[q]);
        hbits[q] = f2b(hvq);
        hv8[q] = (short)hbits[q];
      }
      *(s8_t*)&xh[row][128 + cg * 8] = hv8;   // h_own for next Z / out GEMM
      if (tt < T_ - 1) {
        const int gr = r0 + row, n = gr & 511;
        unsigned short* dst = hP + ((size_t)(tt & 1) * 8 + b) * 65536 +
                              (size_t)(n >> 3) * 1024 + (n & 7);
        #pragma unroll
        for (int q = 0; q < 8; q++) dst[(size_t)(cg * 8 + q) * 8] = hbits[q];
      }
    }
    __syncthreads();   // barrier drains vmcnt: hP writes complete
    if (tt < T_ - 1 && t == 0) {
      __threadfence();
      __hip_atomic_fetch_add(cnt + b * 16, 1, __ATOMIC_RELEASE,
                             __HIP_MEMORY_SCOPE_AGENT);
    }
    // out GEMM: oacc += h @ WoutP + bout ; store out[:, tt]
    f4_t o;
    #pragma unroll
    for (int r = 0; r < 4; r++) o[r] = 0.f;
    for (int kc = 0; kc < 4; kc++) {
      s8_t a = *(const s8_t*)&xh[m][128 + kc * 32 + kg * 8];
      s8_t bf = *(const s8_t*)&WoutP[((size_t)(kc * 4 + kg) * 64 + w * 16 + m) * 8];
      o = __builtin_amdgcn_mfma_f32_16x16x32_bf16(a, bf, o, 0, 0, 0);
    }
    #pragma unroll
    for (int r = 0; r < 4; r++) {
      oacc[r] += o[r] + bo;
      out[((size_t)(r0 + kg * 4 + r) * T_ + tt) * NIN_ + w * 16 + m] = oacc[r];
    }
  }
}

extern "C" void kernel_launch(void* const* d_in, const int* in_sizes, int n_in,
                              void* d_out, int out_size, void* d_ws, size_t ws_size,
                              hipStream_t stream) {
  const float* X    = (const float*)d_in[0];
  const float* A    = (const float*)d_in[1];
  const float* Wse  = (const float*)d_in[2];
  const float* bse  = (const float*)d_in[3];
  const float* Wpe  = (const float*)d_in[4];
  const float* bpe  = (const float*)d_in[5];
  const float* Wii  = (const float*)d_in[6];
  const float* bii  = (const float*)d_in[7];
  const float* Whi  = (const float*)d_in[8];
  const float* bhi  = (const float*)d_in[9];
  const float* Wif  = (const float*)d_in[10];
  const float* bif_ = (const float*)d_in[11];
  const float* Whf  = (const float*)d_in[12];
  const float* bhf  = (const float*)d_in[13];
  const float* Wig  = (const float*)d_in[14];
  const float* big_ = (const float*)d_in[15];
  const float* Whg  = (const float*)d_in[16];
  const float* bhg  = (const float*)d_in[17];
  const float* Wio  = (const float*)d_in[18];
  const float* bio  = (const float*)d_in[19];
  const float* Who  = (const float*)d_in[20];
  const float* bho  = (const float*)d_in[21];
  const float* Wout = (const float*)d_in[22];
  const float* bout = (const float*)d_in[23];
  float* out = (float*)d_out;
  char* ws = (char*)d_ws;

  size_t off = 0;
  float* dinv = (float*)(ws + off);                   off += 4096 * 4;
  float* WC   = (float*)(ws + off);                   off += 65536 * 4;
  float* bcat = (float*)(ws + off);                   off += 512 * 4;
  unsigned short* WUP2  = (unsigned short*)(ws + off); off += 131072 * 2;
  unsigned short* WseP  = (unsigned short*)(ws + off); off += 8192 * 2;
  unsigned short* WxeP  = (unsigned short*)(ws + off); off += 65536 * 2;
  unsigned short* WoutP = (unsigned short*)(ws + off); off += 8192 * 2;
  unsigned short* hP    = (unsigned short*)(ws + off); off += (size_t)2 * 8 * 65536 * 2;
  int* cnt = (int*)(ws + off);                         off += 128 * 4;

  hipMemsetAsync(cnt, 0, 128 * 4, stream);
  k_dinv<<<NR_ / 4, 256, 0, stream>>>(A, dinv);
  k_wc<<<256, 256, 0, stream>>>(Wpe, Wii, Wif, Wig, Wio, WC);
  k_bcat<<<2, 256, 0, stream>>>(bii, bif_, big_, bio, bhi, bhf, bhg, bho, bpe,
                                Wii, Wif, Wig, Wio, bcat);
  k_pack_wu2<<<512, 256, 0, stream>>>(WC, Whi, Whf, Whg, Who, WUP2);
  k_pack_misc<<<320, 256, 0, stream>>>(Wse, Wii, Wif, Wig, Wio, Wout,
                                       WseP, WxeP, WoutP);

  void* args[] = {(void*)&A, (void*)&dinv, (void*)&X,
                  (void*)&WseP, (void*)&bse, (void*)&WxeP, (void*)&bcat,
                  (void*)&WUP2, (void*)&WoutP, (void*)&bout,
                  (void*)&hP, (void*)&cnt, (void*)&out};
  if (hipLaunchCooperativeKernel((const void*)k_persist, dim3(256), dim3(256),
                                 args, 0, stream) != hipSuccess) {
    // fallback: plain launch; grid == CU count with 1 block/CU co-resides
    k_persist<<<256, 256, 0, stream>>>(A, dinv, X, WseP, bse, WxeP, bcat,
                                       WUP2, WoutP, bout, hP, cnt, out);
  }
}

// Round 4
// 755.008 us; speedup vs baseline: 3.0853x; 3.0853x over previous
//
#include <hip/hip_runtime.h>
#include <math.h>

#define B_ 8
#define N_ 512
#define T_ 64
#define NIN_ 64
#define NE_ 128
#define NH_ 128
#define NR_ 4096   // B*N

typedef __attribute__((ext_vector_type(8))) short s8_t;   // 8 bf16 = 16B
typedef __attribute__((ext_vector_type(4))) float f4_t;
typedef __attribute__((ext_vector_type(4))) int i4_t;

__device__ __forceinline__ float sigm(float x) {
  x = fminf(fmaxf(x, -30.f), 30.f);
  return 1.f / (1.f + __expf(-x));
}
__device__ __forceinline__ float tanh_fast(float x) {
  x = fminf(fmaxf(x, -15.f), 15.f);
  float e = __expf(2.f * x);
  return (e - 1.f) / (e + 1.f);
}
__device__ __forceinline__ unsigned short f2b(float f) {
  union { float f; unsigned u; } v; v.f = f;
  unsigned r = (v.u + 0x7FFFu + ((v.u >> 16) & 1u)) >> 16;
  return (unsigned short)r;
}

// coherent (L1/L2-bypass, L3-direct) 16B load/store — no cache maintenance
__device__ __forceinline__ i4_t load_coherent16(const void* p) {
  i4_t r;
  asm volatile("global_load_dwordx4 %0, %1, off sc0 sc1"
               : "=v"(r) : "v"(p) : "memory");
  return r;
}
__device__ __forceinline__ void store_coherent16(void* p, i4_t v) {
  asm volatile("global_store_dwordx4 %0, %1, off sc0 sc1"
               :: "v"(p), "v"(v) : "memory");
}
__device__ __forceinline__ void wait_vm0() {
  asm volatile("s_waitcnt vmcnt(0)" ::: "memory");
}

// ---------------- one-time setup kernels ----------------

__global__ __launch_bounds__(256) void k_dinv(const float* __restrict__ A,
                                              float* __restrict__ dinv) {
  int row = blockIdx.x * 4 + (threadIdx.x >> 6);
  int lane = threadIdx.x & 63;
  const float* a = A + (size_t)row * N_;
  float s = 0.f;
  for (int j = lane; j < N_; j += 64) s += a[j];
  #pragma unroll
  for (int off = 32; off > 0; off >>= 1) s += __shfl_down(s, off);
  if (lane == 0) dinv[row] = (s > 0.f) ? rsqrtf(s) : 0.f;
}

// WC (fp32, [128][512]) = Wpe @ concat(Wx*[128:256,:])
__global__ __launch_bounds__(256) void k_wc(
    const float* __restrict__ Wpe,
    const float* __restrict__ Wii, const float* __restrict__ Wif,
    const float* __restrict__ Wig, const float* __restrict__ Wio,
    float* __restrict__ WC) {
  int idx = blockIdx.x * 256 + threadIdx.x;    // 65536
  int k = idx >> 9, col = idx & 511, g = col >> 7, j = col & 127;
  const float* Wx = (g == 0) ? Wii : (g == 1) ? Wif : (g == 2) ? Wig : Wio;
  float s = 0.f;
  for (int mm = 0; mm < 128; mm++)
    s += Wpe[(size_t)k * 128 + mm] * Wx[(size_t)(128 + mm) * 128 + j];
  WC[idx] = s;
}

// bcat[col] = bx + bh + bpe @ W*[128:256]
__global__ __launch_bounds__(256) void k_bcat(
    const float* __restrict__ bii, const float* __restrict__ bif,
    const float* __restrict__ big, const float* __restrict__ bio,
    const float* __restrict__ bhi, const float* __restrict__ bhf,
    const float* __restrict__ bhg, const float* __restrict__ bho,
    const float* __restrict__ bpe,
    const float* __restrict__ Wii, const float* __restrict__ Wif,
    const float* __restrict__ Wig, const float* __restrict__ Wio,
    float* __restrict__ bcat) {
  int col = blockIdx.x * 256 + threadIdx.x;   // < 512
  int g = col >> 7, j = col & 127;
  const float* bx = (g == 0) ? bii : (g == 1) ? bif : (g == 2) ? big : bio;
  const float* bh = (g == 0) ? bhi : (g == 1) ? bhf : (g == 2) ? bhg : bho;
  const float* Wx = (g == 0) ? Wii : (g == 1) ? Wif : (g == 2) ? Wig : Wio;
  float s = bx[j] + bh[j];
  for (int k = 0; k < NE_; k++) s += bpe[k] * Wx[(size_t)(128 + k) * NH_ + j];
  bcat[col] = s;
}

// WUP2 (bf16 k-packed [(256/8)][512][8]): rows 0:128 = WC, 128:256 = Wh*
__global__ __launch_bounds__(256) void k_pack_wu2(
    const float* __restrict__ WC,
    const float* __restrict__ Whi, const float* __restrict__ Whf,
    const float* __restrict__ Whg, const float* __restrict__ Who,
    unsigned short* __restrict__ WUP2) {
  int idx = blockIdx.x * 256 + threadIdx.x;    // 131072
  int k = idx >> 9, col = idx & 511, g = col >> 7, j = col & 127;
  float v;
  if (k < 128) v = WC[(size_t)k * 512 + col];
  else {
    const float* Wh = (g == 0) ? Whi : (g == 1) ? Whf : (g == 2) ? Whg : Who;
    v = Wh[(size_t)(k - 128) * 128 + j];
  }
  WUP2[((size_t)(k >> 3) * 512 + col) * 8 + (k & 7)] = f2b(v);
}

// WseP [(64/8)][128][8], WxeP [(128/8)][512][8], WoutP [(128/8)][64][8]
__global__ __launch_bounds__(256) void k_pack_misc(
    const float* __restrict__ Wse,
    const float* __restrict__ Wii, const float* __restrict__ Wif,
    const float* __restrict__ Wig, const float* __restrict__ Wio,
    const float* __restrict__ Wout,
    unsigned short* __restrict__ WseP, unsigned short* __restrict__ WxeP,
    unsigned short* __restrict__ WoutP) {
  int idx = blockIdx.x * 256 + threadIdx.x;    // 81920
  if (idx < 8192) {
    int k = idx >> 7, c = idx & 127;
    WseP[((size_t)(k >> 3) * 128 + c) * 8 + (k & 7)] = f2b(Wse[(size_t)k * 128 + c]);
  } else if (idx < 8192 + 65536) {
    int i = idx - 8192;
    int k = i >> 9, col = i & 511, g = col >> 7, j = col & 127;
    const float* Wx = (g == 0) ? Wii : (g == 1) ? Wif : (g == 2) ? Wig : Wio;
    WxeP[((size_t)(k >> 3) * 512 + col) * 8 + (k & 7)] = f2b(Wx[(size_t)k * 128 + j]);
  } else if (idx < 8192 + 65536 + 8192) {
    int i = idx - 8192 - 65536;
    int k = i >> 6, c = i & 63;
    WoutP[((size_t)(k >> 3) * 64 + c) * 8 + (k & 7)] = f2b(Wout[(size_t)k * 64 + c]);
  }
}

// ---------------- persistent fused kernel ----------------
// 256 blocks x 256 threads; block g owns rows r0=16g..16g+15; batch b = g>>5.
// Cross-block h exchange: write-through sc0sc1 stores -> L3; coherent sc0sc1
// loads <- L3; monotone counters with RELAXED system-scope atomics.
// NO fences / cache-wide maintenance -> WUP2 etc. stay L2-resident.
__global__ __launch_bounds__(256, 1) void k_persist(
    const float* __restrict__ A, const float* __restrict__ dinv,
    const float* __restrict__ X,
    const unsigned short* __restrict__ WseP, const float* __restrict__ bse,
    const unsigned short* __restrict__ WxeP, const float* __restrict__ bcat,
    const unsigned short* __restrict__ WUP2,
    const unsigned short* __restrict__ WoutP, const float* __restrict__ bout,
    unsigned short* __restrict__ hP,   // [2][8][64*128*8]
    int* __restrict__ cnt,             // [8*16]
    float* __restrict__ out) {
  __shared__ __align__(16) unsigned short as[16][520];   // scaled A rows, bf16
  __shared__ __align__(16) unsigned short xh[16][264];   // [G | h_own] bf16
  __shared__ __align__(16) float zb[4][16][132];         // gate exchange

  const int t = threadIdx.x;
  const int g = blockIdx.x;
  const int r0 = g * 16;
  const int b = g >> 5;
  const int l = t & 63, w = t >> 6, m = l & 15, kg = l >> 4;

  float* X0s = &zb[0][0][0];   // 1024 floats (prologue only)
  float* dvb = X0s + 1024;     // 512 floats (prologue only)

  // ---- prologue: stage inputs, compute espre into registers ----
  for (int i = t; i < 512; i += 256) dvb[i] = dinv[b * 512 + i];
  for (int i = t; i < 1024; i += 256) {
    int r = i >> 6, c = i & 63;
    float v = X[((size_t)(r0 + r) * T_) * NIN_ + c];
    X0s[i] = v;
    out[((size_t)(r0 + r) * T_) * NIN_ + c] = v;   // out[:, t=0] = X0
  }
  __syncthreads();
  for (int i = t; i < 1024; i += 256) xh[i >> 6][i & 63] = f2b(X0s[i]);
  for (int i = t; i < 8192; i += 256) {
    int r = i >> 9, k = i & 511;
    as[r][k] = f2b(A[(size_t)(r0 + r) * 512 + k] * dinv[r0 + r] * dvb[k]);
  }
  __syncthreads();
  // es = X0 @ WseP + bse -> bf16 -> xh[:,128:256]
  {
    f4_t e[2];
    #pragma unroll
    for (int nt = 0; nt < 2; nt++) {
      float bv = bse[w * 32 + nt * 16 + m];
      #pragma unroll
      for (int r = 0; r < 4; r++) e[nt][r] = bv;
    }
    for (int kc = 0; kc < 2; kc++) {
      s8_t a = *(const s8_t*)&xh[m][kc * 32 + kg * 8];
      #pragma unroll
      for (int nt = 0; nt < 2; nt++) {
        s8_t bf = *(const s8_t*)&WseP[((size_t)(kc * 4 + kg) * 128 + w * 32 + nt * 16 + m) * 8];
        e[nt] = __builtin_amdgcn_mfma_f32_16x16x32_bf16(a, bf, e[nt], 0, 0, 0);
      }
    }
    #pragma unroll
    for (int nt = 0; nt < 2; nt++)
      #pragma unroll
      for (int r = 0; r < 4; r++)
        xh[kg * 4 + r][128 + w * 32 + nt * 16 + m] = f2b(e[nt][r]);
  }
  __syncthreads();
  // espre (Z-GEMM acc init) in registers: esr = es @ WxeP + bcat (C-layout)
  f4_t esr[8];
  #pragma unroll
  for (int nt = 0; nt < 8; nt++) {
    float bv = bcat[w * 128 + nt * 16 + m];
    #pragma unroll
    for (int r = 0; r < 4; r++) esr[nt][r] = bv;
  }
  for (int kc = 0; kc < 4; kc++) {
    s8_t a = *(const s8_t*)&xh[m][128 + kc * 32 + kg * 8];
    #pragma unroll
    for (int nt = 0; nt < 8; nt++) {
      s8_t bf = *(const s8_t*)&WxeP[((size_t)(kc * 4 + kg) * 512 + w * 128 + nt * 16 + m) * 8];
      esr[nt] = __builtin_amdgcn_mfma_f32_16x16x32_bf16(a, bf, esr[nt], 0, 0, 0);
    }
  }
  // persistent per-thread state
  f4_t oacc;
  #pragma unroll
  for (int r = 0; r < 4; r++) oacc[r] = X0s[(kg * 4 + r) * 64 + w * 16 + m];
  const float bo = bout[w * 16 + m];
  float cs[8];
  #pragma unroll
  for (int q = 0; q < 8; q++) cs[q] = 0.f;
  __syncthreads();
  for (int i = t; i < 16 * 264; i += 256) ((unsigned short*)xh)[i] = 0;
  __syncthreads();

  // ---- main loop over timesteps ----
  for (int tt = 1; tt < T_; tt++) {
    if (tt > 1) {
      // wait for all 32 blocks of this batch to publish h^{tt-1}
      if (t == 0) {
        const int need = 32 * (tt - 1);
        while (__hip_atomic_load(cnt + b * 16, __ATOMIC_RELAXED,
                                 __HIP_MEMORY_SCOPE_SYSTEM) < need)
          __builtin_amdgcn_s_sleep(2);
      }
      __syncthreads();
      // graph GEMM: G(own rows) = as @ h_batch, B-frags coherent from L3
      const unsigned short* hPb =
          hP + ((size_t)((tt - 1) & 1) * 8 + b) * 65536;
      i4_t hf[16][2];
      #pragma unroll
      for (int kc = 0; kc < 16; kc++)
        #pragma unroll
        for (int nt = 0; nt < 2; nt++)
          hf[kc][nt] = load_coherent16(
              &hPb[((size_t)(kc * 4 + kg) * 128 + w * 32 + nt * 16 + m) * 8]);
      wait_vm0();
      f4_t gacc[2];
      #pragma unroll
      for (int nt = 0; nt < 2; nt++)
        #pragma unroll
        for (int r = 0; r < 4; r++) gacc[nt][r] = 0.f;
      #pragma unroll
      for (int kc = 0; kc < 16; kc++) {
        s8_t a = *(const s8_t*)&as[m][kc * 32 + kg * 8];
        #pragma unroll
        for (int nt = 0; nt < 2; nt++) {
          s8_t bf = *(const s8_t*)&hf[kc][nt];
          gacc[nt] = __builtin_amdgcn_mfma_f32_16x16x32_bf16(a, bf, gacc[nt], 0, 0, 0);
        }
      }
      #pragma unroll
      for (int nt = 0; nt < 2; nt++)
        #pragma unroll
        for (int r = 0; r < 4; r++)
          xh[kg * 4 + r][w * 32 + nt * 16 + m] = f2b(gacc[nt][r]);
      __syncthreads();
    }
    // Z-GEMM: acc = espre + [G|h] @ WUP2   (WUP2 via plain cached loads: L2-hot)
    f4_t acc[8];
    #pragma unroll
    for (int nt = 0; nt < 8; nt++) acc[nt] = esr[nt];
    for (int kc = 0; kc < 8; kc++) {
      s8_t a = *(const s8_t*)&xh[m][kc * 32 + kg * 8];
      #pragma unroll
      for (int nt = 0; nt < 8; nt++) {
        s8_t bf = *(const s8_t*)&WUP2[((size_t)(kc * 4 + kg) * 512 + w * 128 + nt * 16 + m) * 8];
        acc[nt] = __builtin_amdgcn_mfma_f32_16x16x32_bf16(a, bf, acc[nt], 0, 0, 0);
      }
    }
    #pragma unroll
    for (int nt = 0; nt < 8; nt++)
      #pragma unroll
      for (int r = 0; r < 4; r++)
        zb[w][kg * 4 + r][nt * 16 + m] = acc[nt][r];
    __syncthreads();
    // cell update: thread owns (row = t>>4, cols (t&15)*8..+7); c-state in regs
    {
      const int row = t >> 4, cg = t & 15;
      float zi[8], zf[8], zg[8], zo[8];
      *(f4_t*)&zi[0] = *(f4_t*)&zb[0][row][cg * 8];
      *(f4_t*)&zi[4] = *(f4_t*)&zb[0][row][cg * 8 + 4];
      *(f4_t*)&zf[0] = *(f4_t*)&zb[1][row][cg * 8];
      *(f4_t*)&zf[4] = *(f4_t*)&zb[1][row][cg * 8 + 4];
      *(f4_t*)&zg[0] = *(f4_t*)&zb[2][row][cg * 8];
      *(f4_t*)&zg[4] = *(f4_t*)&zb[2][row][cg * 8 + 4];
      *(f4_t*)&zo[0] = *(f4_t*)&zb[3][row][cg * 8];
      *(f4_t*)&zo[4] = *(f4_t*)&zb[3][row][cg * 8 + 4];
      s8_t hv8;
      #pragma unroll
      for (int q = 0; q < 8; q++) {
        float it = sigm(zi[q]), ft = sigm(zf[q]);
        float gt = tanh_fast(zg[q]), ot = sigm(zo[q]);
        cs[q] = ft * cs[q] + it * gt;
        float hvq = ot * tanh_fast(cs[q]);
        hv8[q] = (short)f2b(hvq);
      }
      *(s8_t*)&xh[row][128 + cg * 8] = hv8;   // h_own for next Z / out GEMM
    }
    __syncthreads();
    // publish h: LDS transpose -> one contiguous 16B write-through store/thread
    if (tt < T_ - 1) {
      const int grp = t & 1, c = t >> 1;   // 8 rows x 1 col per thread
      unsigned short tmp[8];
      #pragma unroll
      for (int q = 0; q < 8; q++) tmp[q] = xh[grp * 8 + q][128 + c];
      const int n0 = (r0 & 511) + grp * 8;
      unsigned short* dst = hP + ((size_t)(tt & 1) * 8 + b) * 65536 +
                            (size_t)(n0 >> 3) * 1024 + (size_t)c * 8;
      store_coherent16(dst, *(i4_t*)tmp);
      wait_vm0();   // stores visible at L3 before counter bump
    }
    __syncthreads();
    if (tt < T_ - 1 && t == 0)
      __hip_atomic_fetch_add(cnt + b * 16, 1, __ATOMIC_RELAXED,
                             __HIP_MEMORY_SCOPE_SYSTEM);
    // out GEMM: oacc += h @ WoutP + bout ; store out[:, tt]
    f4_t o;
    #pragma unroll
    for (int r = 0; r < 4; r++) o[r] = 0.f;
    for (int kc = 0; kc < 4; kc++) {
      s8_t a = *(const s8_t*)&xh[m][128 + kc * 32 + kg * 8];
      s8_t bf = *(const s8_t*)&WoutP[((size_t)(kc * 4 + kg) * 64 + w * 16 + m) * 8];
      o = __builtin_amdgcn_mfma_f32_16x16x32_bf16(a, bf, o, 0, 0, 0);
    }
    #pragma unroll
    for (int r = 0; r < 4; r++) {
      oacc[r] += o[r] + bo;
      out[((size_t)(r0 + kg * 4 + r) * T_ + tt) * NIN_ + w * 16 + m] = oacc[r];
    }
  }
}

extern "C" void kernel_launch(void* const* d_in, const int* in_sizes, int n_in,
                              void* d_out, int out_size, void* d_ws, size_t ws_size,
                              hipStream_t stream) {
  const float* X    = (const float*)d_in[0];
  const float* A    = (const float*)d_in[1];
  const float* Wse  = (const float*)d_in[2];
  const float* bse  = (const float*)d_in[3];
  const float* Wpe  = (const float*)d_in[4];
  const float* bpe  = (const float*)d_in[5];
  const float* Wii  = (const float*)d_in[6];
  const float* bii  = (const float*)d_in[7];
  const float* Whi  = (const float*)d_in[8];
  const float* bhi  = (const float*)d_in[9];
  const float* Wif  = (const float*)d_in[10];
  const float* bif_ = (const float*)d_in[11];
  const float* Whf  = (const float*)d_in[12];
  const float* bhf  = (const float*)d_in[13];
  const float* Wig  = (const float*)d_in[14];
  const float* big_ = (const float*)d_in[15];
  const float* Whg  = (const float*)d_in[16];
  const float* bhg  = (const float*)d_in[17];
  const float* Wio  = (const float*)d_in[18];
  const float* bio  = (const float*)d_in[19];
  const float* Who  = (const float*)d_in[20];
  const float* bho  = (const float*)d_in[21];
  const float* Wout = (const float*)d_in[22];
  const float* bout = (const float*)d_in[23];
  float* out = (float*)d_out;
  char* ws = (char*)d_ws;

  size_t off = 0;
  float* dinv = (float*)(ws + off);                   off += 4096 * 4;
  float* WC   = (float*)(ws + off);                   off += 65536 * 4;
  float* bcat = (float*)(ws + off);                   off += 512 * 4;
  unsigned short* WUP2  = (unsigned short*)(ws + off); off += 131072 * 2;
  unsigned short* WseP  = (unsigned short*)(ws + off); off += 8192 * 2;
  unsigned short* WxeP  = (unsigned short*)(ws + off); off += 65536 * 2;
  unsigned short* WoutP = (unsigned short*)(ws + off); off += 8192 * 2;
  unsigned short* hP    = (unsigned short*)(ws + off); off += (size_t)2 * 8 * 65536 * 2;
  int* cnt = (int*)(ws + off);                         off += 128 * 4;

  hipMemsetAsync(cnt, 0, 128 * 4, stream);
  k_dinv<<<NR_ / 4, 256, 0, stream>>>(A, dinv);
  k_wc<<<256, 256, 0, stream>>>(Wpe, Wii, Wif, Wig, Wio, WC);
  k_bcat<<<2, 256, 0, stream>>>(bii, bif_, big_, bio, bhi, bhf, bhg, bho, bpe,
                                Wii, Wif, Wig, Wio, bcat);
  k_pack_wu2<<<512, 256, 0, stream>>>(WC, Whi, Whf, Whg, Who, WUP2);
  k_pack_misc<<<320, 256, 0, stream>>>(Wse, Wii, Wif, Wig, Wio, Wout,
                                       WseP, WxeP, WoutP);

  void* args[] = {(void*)&A, (void*)&dinv, (void*)&X,
                  (void*)&WseP, (void*)&bse, (void*)&WxeP, (void*)&bcat,
                  (void*)&WUP2, (void*)&WoutP, (void*)&bout,
                  (void*)&hP, (void*)&cnt, (void*)&out};
  if (hipLaunchCooperativeKernel((const void*)k_persist, dim3(256), dim3(256),
                                 args, 0, stream) != hipSuccess) {
    // fallback: plain launch; grid == CU count with 1 block/CU co-resides
    k_persist<<<256, 256, 0, stream>>>(A, dinv, X, WseP, bse, WxeP, bcat,
                                       WUP2, WoutP, bout, hP, cnt, out);
  }
}

// Round 5
// 626.496 us; speedup vs baseline: 3.7182x; 1.2051x over previous
//
#include <hip/hip_runtime.h>
#include <math.h>

#define B_ 8
#define N_ 512
#define T_ 64
#define NIN_ 64
#define NE_ 128
#define NH_ 128
#define NR_ 4096   // B*N

typedef __attribute__((ext_vector_type(8))) short s8_t;   // 8 bf16 = 16B
typedef __attribute__((ext_vector_type(4))) short s4_t;   // 4 bf16 = 8B
typedef __attribute__((ext_vector_type(4))) float f4_t;
typedef __attribute__((ext_vector_type(4))) int i4_t;

__device__ __forceinline__ float sigm(float x) {
  x = fminf(fmaxf(x, -30.f), 30.f);
  return 1.f / (1.f + __expf(-x));
}
__device__ __forceinline__ float tanh_fast(float x) {
  x = fminf(fmaxf(x, -15.f), 15.f);
  float e = __expf(2.f * x);
  return (e - 1.f) / (e + 1.f);
}
__device__ __forceinline__ unsigned short f2b(float f) {
  union { float f; unsigned u; } v; v.f = f;
  unsigned r = (v.u + 0x7FFFu + ((v.u >> 16) & 1u)) >> 16;
  return (unsigned short)r;
}

// coherent (cache-state-neutral) 16B load/store via L3 — no cache maintenance
__device__ __forceinline__ i4_t load_coherent16(const void* p) {
  i4_t r;
  asm volatile("global_load_dwordx4 %0, %1, off sc0 sc1"
               : "=v"(r) : "v"(p) : "memory");
  return r;
}
__device__ __forceinline__ void store_coherent16(void* p, i4_t v) {
  asm volatile("global_store_dwordx4 %0, %1, off sc0 sc1"
               :: "v"(p), "v"(v) : "memory");
}
__device__ __forceinline__ void wait_vm0() {
  asm volatile("s_waitcnt vmcnt(0)" ::: "memory");
}

// ---------------- fused setup kernel 1: dinv + bcat + pack_misc + cnt ----
__global__ __launch_bounds__(256) void k_setup1(
    const float* __restrict__ A,
    const float* __restrict__ bii, const float* __restrict__ bif,
    const float* __restrict__ big, const float* __restrict__ bio,
    const float* __restrict__ bhi, const float* __restrict__ bhf,
    const float* __restrict__ bhg, const float* __restrict__ bho,
    const float* __restrict__ bpe,
    const float* __restrict__ Wii, const float* __restrict__ Wif,
    const float* __restrict__ Wig, const float* __restrict__ Wio,
    const float* __restrict__ Wse, const float* __restrict__ Wout,
    float* __restrict__ dinv, float* __restrict__ bcat,
    unsigned short* __restrict__ WseP, unsigned short* __restrict__ WxeP,
    unsigned short* __restrict__ WoutP, int* __restrict__ cnt) {
  const int blk = blockIdx.x, t = threadIdx.x;
  if (blk < 1024) {                       // dinv: wave per row
    int row = blk * 4 + (t >> 6);
    int lane = t & 63;
    const float* a = A + (size_t)row * N_;
    float s = 0.f;
    for (int j = lane; j < N_; j += 64) s += a[j];
    #pragma unroll
    for (int off = 32; off > 0; off >>= 1) s += __shfl_down(s, off);
    if (lane == 0) dinv[row] = (s > 0.f) ? rsqrtf(s) : 0.f;
  } else if (blk < 1026) {                // bcat
    int col = (blk - 1024) * 256 + t;
    int g = col >> 7, j = col & 127;
    const float* bx = (g == 0) ? bii : (g == 1) ? bif : (g == 2) ? big : bio;
    const float* bh = (g == 0) ? bhi : (g == 1) ? bhf : (g == 2) ? bhg : bho;
    const float* Wx = (g == 0) ? Wii : (g == 1) ? Wif : (g == 2) ? Wig : Wio;
    float s = bx[j] + bh[j];
    for (int k = 0; k < NE_; k++) s += bpe[k] * Wx[(size_t)(128 + k) * NH_ + j];
    bcat[col] = s;
  } else if (blk < 1346) {                // pack WseP / WxeP / WoutP
    int idx = (blk - 1026) * 256 + t;     // < 81920
    if (idx < 8192) {
      int k = idx >> 7, c = idx & 127;
      WseP[((size_t)(k >> 3) * 128 + c) * 8 + (k & 7)] = f2b(Wse[(size_t)k * 128 + c]);
    } else if (idx < 8192 + 65536) {
      int i = idx - 8192;
      int k = i >> 9, col = i & 511, g = col >> 7, j = col & 127;
      const float* Wx = (g == 0) ? Wii : (g == 1) ? Wif : (g == 2) ? Wig : Wio;
      WxeP[((size_t)(k >> 3) * 512 + col) * 8 + (k & 7)] = f2b(Wx[(size_t)k * 128 + j]);
    } else if (idx < 8192 + 65536 + 8192) {
      int i = idx - 8192 - 65536;
      int k = i >> 6, c = i & 63;
      WoutP[((size_t)(k >> 3) * 64 + c) * 8 + (k & 7)] = f2b(Wout[(size_t)k * 64 + c]);
    }
  } else {                                // zero sync counters
    if (t < 128) cnt[t] = 0;
  }
}

// ---------------- fused setup kernel 2: WUP2 (WC dot inlined) ------------
// WUP2 (bf16 k-packed [(256/8)][512][8]): rows 0:128 = Wpe@Wx[128:256],
// rows 128:256 = Wh*
__global__ __launch_bounds__(256) void k_setup2(
    const float* __restrict__ Wpe,
    const float* __restrict__ Whi, const float* __restrict__ Whf,
    const float* __restrict__ Whg, const float* __restrict__ Who,
    const float* __restrict__ Wii, const float* __restrict__ Wif,
    const float* __restrict__ Wig, const float* __restrict__ Wio,
    unsigned short* __restrict__ WUP2) {
  int idx = blockIdx.x * 256 + threadIdx.x;    // 131072
  int k = idx >> 9, col = idx & 511, g = col >> 7, j = col & 127;
  float v;
  if (k < 128) {
    const float* Wx = (g == 0) ? Wii : (g == 1) ? Wif : (g == 2) ? Wig : Wio;
    float s = 0.f;
    for (int mm = 0; mm < 128; mm++)
      s += Wpe[(size_t)k * 128 + mm] * Wx[(size_t)(128 + mm) * 128 + j];
    v = s;
  } else {
    const float* Wh = (g == 0) ? Whi : (g == 1) ? Whf : (g == 2) ? Whg : Who;
    v = Wh[(size_t)(k - 128) * 128 + j];
  }
  WUP2[((size_t)(k >> 3) * 512 + col) * 8 + (k & 7)] = f2b(v);
}

// ---------------- persistent fused kernel ----------------
// 256 blocks x 512 threads (8 waves, 2/SIMD); block g owns rows 16g..16g+15;
// batch b = g>>5. Z-GEMM weights pinned in VGPRs: wave w owns Z cols
// [64w, 64w+64) -> 8(kc) x 4(nt) x 16B = 512 B/lane = 128 VGPRs.
// Cross-block h exchange: sc0sc1 write-through stores / coherent loads via L3,
// monotone counters with RELAXED system-scope atomics (no cache maintenance).
__global__ __launch_bounds__(512, 2) void k_persist(
    const float* __restrict__ A, const float* __restrict__ dinv,
    const float* __restrict__ X,
    const unsigned short* __restrict__ WseP, const float* __restrict__ bse,
    const unsigned short* __restrict__ WxeP, const float* __restrict__ bcat,
    const unsigned short* __restrict__ WUP2,
    const unsigned short* __restrict__ WoutP, const float* __restrict__ bout,
    unsigned short* __restrict__ hP,   // [2][8][64*128*8]
    int* __restrict__ cnt,             // [8*16]
    float* __restrict__ out) {
  __shared__ __align__(16) unsigned short as[16][520];   // scaled A rows, bf16
  __shared__ __align__(16) unsigned short xh[16][264];   // [G | h_own] bf16
  __shared__ __align__(16) float zb[4][16][132];         // gate exchange

  const int t = threadIdx.x;
  const int g = blockIdx.x;
  const int r0 = g * 16;
  const int b = g >> 5;
  const int l = t & 63, w = t >> 6, m = l & 15, kg = l >> 4;

  float* X0s = &zb[0][0][0];   // 1024 floats (prologue scratch)
  float* dvb = X0s + 1024;     // 512 floats (prologue scratch)

  // ---- prologue ----
  if (t < 512) dvb[t] = dinv[b * 512 + t];
  for (int i = t; i < 1024; i += 512) {
    int r = i >> 6, c = i & 63;
    float v = X[((size_t)(r0 + r) * T_) * NIN_ + c];
    X0s[i] = v;
    out[((size_t)(r0 + r) * T_) * NIN_ + c] = v;   // out[:, t=0] = X0
  }
  __syncthreads();
  for (int i = t; i < 1024; i += 512) xh[i >> 6][i & 63] = f2b(X0s[i]);
  for (int i = t; i < 8192; i += 512) {
    int r = i >> 9, k = i & 511;
    as[r][k] = f2b(A[(size_t)(r0 + r) * 512 + k] * dinv[r0 + r] * dvb[k]);
  }
  __syncthreads();
  // es = X0 @ WseP + bse -> bf16 -> xh[:,128:256]; wave w: cols 16w..16w+15
  {
    f4_t e;
    float bv = bse[w * 16 + m];
    #pragma unroll
    for (int r = 0; r < 4; r++) e[r] = bv;
    #pragma unroll
    for (int kc = 0; kc < 2; kc++) {
      s8_t a = *(const s8_t*)&xh[m][kc * 32 + kg * 8];
      s8_t bf = *(const s8_t*)&WseP[((size_t)(kc * 4 + kg) * 128 + w * 16 + m) * 8];
      e = __builtin_amdgcn_mfma_f32_16x16x32_bf16(a, bf, e, 0, 0, 0);
    }
    #pragma unroll
    for (int r = 0; r < 4; r++)
      xh[kg * 4 + r][128 + w * 16 + m] = f2b(e[r]);
  }
  __syncthreads();
  // espre in registers: esr = es @ WxeP + bcat; wave w: Z cols 64w..64w+63
  f4_t esr[4];
  #pragma unroll
  for (int nt = 0; nt < 4; nt++) {
    float bv = bcat[w * 64 + nt * 16 + m];
    #pragma unroll
    for (int r = 0; r < 4; r++) esr[nt][r] = bv;
  }
  #pragma unroll
  for (int kc = 0; kc < 4; kc++) {
    s8_t a = *(const s8_t*)&xh[m][128 + kc * 32 + kg * 8];
    #pragma unroll
    for (int nt = 0; nt < 4; nt++) {
      s8_t bf = *(const s8_t*)&WxeP[((size_t)(kc * 4 + kg) * 512 + w * 64 + nt * 16 + m) * 8];
      esr[nt] = __builtin_amdgcn_mfma_f32_16x16x32_bf16(a, bf, esr[nt], 0, 0, 0);
    }
  }
  // persistent per-thread state
  f4_t oacc = {0.f, 0.f, 0.f, 0.f};
  float bo = 0.f;
  if (w < 4) {
    bo = bout[w * 16 + m];
    #pragma unroll
    for (int r = 0; r < 4; r++) oacc[r] = X0s[(kg * 4 + r) * 64 + w * 16 + m];
  }
  float cs[4] = {0.f, 0.f, 0.f, 0.f};   // c-state (cell mapping: row=t>>5, cols (t&31)*4)
  // pin Z-GEMM weights in VGPRs (512 B/lane = 128 VGPRs)
  s8_t wz[8][4];
  #pragma unroll
  for (int kc = 0; kc < 8; kc++)
    #pragma unroll
    for (int nt = 0; nt < 4; nt++)
      wz[kc][nt] = *(const s8_t*)&WUP2[((size_t)(kc * 4 + kg) * 512 + w * 64 + nt * 16 + m) * 8];
  __syncthreads();
  for (int i = t; i < 16 * 264; i += 512) ((unsigned short*)xh)[i] = 0;
  __syncthreads();

  // ---- main loop over timesteps ----
  for (int tt = 1; tt < T_; tt++) {
    if (tt > 1) {
      if (t == 0) {
        const int need = 32 * (tt - 1);
        while (__hip_atomic_load(cnt + b * 16, __ATOMIC_RELAXED,
                                 __HIP_MEMORY_SCOPE_SYSTEM) < need)
          __builtin_amdgcn_s_sleep(2);
      }
      __syncthreads();
      // graph GEMM: wave w computes G cols 16w..16w+15, K=512 from L3
      const unsigned short* hPb =
          hP + ((size_t)((tt - 1) & 1) * 8 + b) * 65536;
      i4_t hf[16];
      #pragma unroll
      for (int kc = 0; kc < 16; kc++)
        hf[kc] = load_coherent16(
            &hPb[((size_t)(kc * 4 + kg) * 128 + w * 16 + m) * 8]);
      wait_vm0();
      f4_t ga = {0.f, 0.f, 0.f, 0.f};
      #pragma unroll
      for (int kc = 0; kc < 16; kc++) {
        s8_t a = *(const s8_t*)&as[m][kc * 32 + kg * 8];
        ga = __builtin_amdgcn_mfma_f32_16x16x32_bf16(a, *(const s8_t*)&hf[kc],
                                                     ga, 0, 0, 0);
      }
      #pragma unroll
      for (int r = 0; r < 4; r++)
        xh[kg * 4 + r][w * 16 + m] = f2b(ga[r]);
      __syncthreads();
    }
    // Z-GEMM: acc = espre + [G|h] @ wz (weights in registers)
    f4_t acc[4];
    #pragma unroll
    for (int nt = 0; nt < 4; nt++) acc[nt] = esr[nt];
    #pragma unroll
    for (int kc = 0; kc < 8; kc++) {
      s8_t a = *(const s8_t*)&xh[m][kc * 32 + kg * 8];
      #pragma unroll
      for (int nt = 0; nt < 4; nt++)
        acc[nt] = __builtin_amdgcn_mfma_f32_16x16x32_bf16(a, wz[kc][nt], acc[nt], 0, 0, 0);
    }
    #pragma unroll
    for (int nt = 0; nt < 4; nt++)
      #pragma unroll
      for (int r = 0; r < 4; r++)
        zb[w >> 1][kg * 4 + r][(w & 1) * 64 + nt * 16 + m] = acc[nt][r];
    __syncthreads();
    // cell update: thread owns (row = t>>5, cols (t&31)*4..+3)
    {
      const int row = t >> 5, cg = t & 31;
      f4_t zi = *(const f4_t*)&zb[0][row][cg * 4];
      f4_t zf = *(const f4_t*)&zb[1][row][cg * 4];
      f4_t zg = *(const f4_t*)&zb[2][row][cg * 4];
      f4_t zo = *(const f4_t*)&zb[3][row][cg * 4];
      s4_t hv4;
      #pragma unroll
      for (int q = 0; q < 4; q++) {
        float it = sigm(zi[q]), ft = sigm(zf[q]);
        float gt = tanh_fast(zg[q]), ot = sigm(zo[q]);
        cs[q] = ft * cs[q] + it * gt;
        hv4[q] = (short)f2b(ot * tanh_fast(cs[q]));
      }
      *(s4_t*)&xh[row][128 + cg * 4] = hv4;
    }
    __syncthreads();
    // publish h (own 16 rows, 4 KB): LDS transpose -> 16B write-through stores
    if (tt < T_ - 1) {
      if (t < 256) {
        const int grp = t & 1, c = t >> 1;
        unsigned short tmp[8];
        #pragma unroll
        for (int q = 0; q < 8; q++) tmp[q] = xh[grp * 8 + q][128 + c];
        unsigned short* dst = hP + ((size_t)(tt & 1) * 8 + b) * 65536 +
                              ((size_t)((r0 & 511) >> 3) + grp) * 1024 +
                              (size_t)c * 8;
        store_coherent16(dst, *(i4_t*)tmp);
      }
      wait_vm0();   // stores visible at L3 before counter bump
      __syncthreads();
      if (t == 0)
        __hip_atomic_fetch_add(cnt + b * 16, 1, __ATOMIC_RELAXED,
                               __HIP_MEMORY_SCOPE_SYSTEM);
    }
    // out GEMM (waves 0..3): oacc += h @ WoutP + bout ; store out[:, tt]
    if (w < 4) {
      f4_t o = {0.f, 0.f, 0.f, 0.f};
      #pragma unroll
      for (int kc = 0; kc < 4; kc++) {
        s8_t a = *(const s8_t*)&xh[m][128 + kc * 32 + kg * 8];
        s8_t bf = *(const s8_t*)&WoutP[((size_t)(kc * 4 + kg) * 64 + w * 16 + m) * 8];
        o = __builtin_amdgcn_mfma_f32_16x16x32_bf16(a, bf, o, 0, 0, 0);
      }
      #pragma unroll
      for (int r = 0; r < 4; r++) {
        oacc[r] += o[r] + bo;
        out[((size_t)(r0 + kg * 4 + r) * T_ + tt) * NIN_ + w * 16 + m] = oacc[r];
      }
    }
  }
}

extern "C" void kernel_launch(void* const* d_in, const int* in_sizes, int n_in,
                              void* d_out, int out_size, void* d_ws, size_t ws_size,
                              hipStream_t stream) {
  const float* X    = (const float*)d_in[0];
  const float* A    = (const float*)d_in[1];
  const float* Wse  = (const float*)d_in[2];
  const float* bse  = (const float*)d_in[3];
  const float* Wpe  = (const float*)d_in[4];
  const float* bpe  = (const float*)d_in[5];
  const float* Wii  = (const float*)d_in[6];
  const float* bii  = (const float*)d_in[7];
  const float* Whi  = (const float*)d_in[8];
  const float* bhi  = (const float*)d_in[9];
  const float* Wif  = (const float*)d_in[10];
  const float* bif_ = (const float*)d_in[11];
  const float* Whf  = (const float*)d_in[12];
  const float* bhf  = (const float*)d_in[13];
  const float* Wig  = (const float*)d_in[14];
  const float* big_ = (const float*)d_in[15];
  const float* Whg  = (const float*)d_in[16];
  const float* bhg  = (const float*)d_in[17];
  const float* Wio  = (const float*)d_in[18];
  const float* bio  = (const float*)d_in[19];
  const float* Who  = (const float*)d_in[20];
  const float* bho  = (const float*)d_in[21];
  const float* Wout = (const float*)d_in[22];
  const float* bout = (const float*)d_in[23];
  float* out = (float*)d_out;
  char* ws = (char*)d_ws;

  size_t off = 0;
  float* dinv = (float*)(ws + off);                    off += 4096 * 4;
  float* bcat = (float*)(ws + off);                    off += 512 * 4;
  unsigned short* WUP2  = (unsigned short*)(ws + off); off += 131072 * 2;
  unsigned short* WseP  = (unsigned short*)(ws + off); off += 8192 * 2;
  unsigned short* WxeP  = (unsigned short*)(ws + off); off += 65536 * 2;
  unsigned short* WoutP = (unsigned short*)(ws + off); off += 8192 * 2;
  unsigned short* hP    = (unsigned short*)(ws + off); off += (size_t)2 * 8 * 65536 * 2;
  int* cnt = (int*)(ws + off);                         off += 128 * 4;

  k_setup1<<<1347, 256, 0, stream>>>(A, bii, bif_, big_, bio, bhi, bhf, bhg,
                                     bho, bpe, Wii, Wif, Wig, Wio, Wse, Wout,
                                     dinv, bcat, WseP, WxeP, WoutP, cnt);
  k_setup2<<<512, 256, 0, stream>>>(Wpe, Whi, Whf, Whg, Who,
                                    Wii, Wif, Wig, Wio, WUP2);

  void* args[] = {(void*)&A, (void*)&dinv, (void*)&X,
                  (void*)&WseP, (void*)&bse, (void*)&WxeP, (void*)&bcat,
                  (void*)&WUP2, (void*)&WoutP, (void*)&bout,
                  (void*)&hP, (void*)&cnt, (void*)&out};
  if (hipLaunchCooperativeKernel((const void*)k_persist, dim3(256), dim3(512),
                                 args, 0, stream) != hipSuccess) {
    // fallback: plain launch; grid == CU count with 1 block/CU co-resides
    k_persist<<<256, 512, 0, stream>>>(A, dinv, X, WseP, bse, WxeP, bcat,
                                       WUP2, WoutP, bout, hP, cnt, out);
  }
}

// Round 6
// 597.506 us; speedup vs baseline: 3.8986x; 1.0485x over previous
//
#include <hip/hip_runtime.h>
#include <math.h>

#define B_ 8
#define N_ 512
#define T_ 64
#define NIN_ 64
#define NE_ 128
#define NH_ 128
#define NR_ 4096   // B*N

typedef __attribute__((ext_vector_type(8))) short s8_t;   // 8 bf16 = 16B
typedef __attribute__((ext_vector_type(4))) short s4_t;   // 4 bf16 = 8B
typedef __attribute__((ext_vector_type(4))) float f4_t;
typedef __attribute__((ext_vector_type(4))) int i4_t;
typedef __attribute__((ext_vector_type(2))) int i2_t;

__device__ __forceinline__ float sigm(float x) {
  x = fminf(fmaxf(x, -30.f), 30.f);
  return 1.f / (1.f + __expf(-x));
}
__device__ __forceinline__ float tanh_fast(float x) {
  x = fminf(fmaxf(x, -15.f), 15.f);
  float e = __expf(2.f * x);
  return (e - 1.f) / (e + 1.f);
}
__device__ __forceinline__ unsigned short f2b(float f) {
  union { float f; unsigned u; } v; v.f = f;
  unsigned r = (v.u + 0x7FFFu + ((v.u >> 16) & 1u)) >> 16;
  return (unsigned short)r;
}

// coherent (cache-state-neutral) loads/stores via L3 — no cache maintenance
__device__ __forceinline__ i4_t load_coherent16(const void* p) {
  i4_t r;
  asm volatile("global_load_dwordx4 %0, %1, off sc0 sc1"
               : "=v"(r) : "v"(p) : "memory");
  return r;
}
__device__ __forceinline__ void store_coherent8(void* p, i2_t v) {
  asm volatile("global_store_dwordx2 %0, %1, off sc0 sc1"
               :: "v"(p), "v"(v) : "memory");
}
__device__ __forceinline__ void wait_vm0() {
  asm volatile("s_waitcnt vmcnt(0)" ::: "memory");
}

// ---------------- fused setup kernel 1: dinv + bcat + pack_misc + cnt ----
__global__ __launch_bounds__(256) void k_setup1(
    const float* __restrict__ A,
    const float* __restrict__ bii, const float* __restrict__ bif,
    const float* __restrict__ big, const float* __restrict__ bio,
    const float* __restrict__ bhi, const float* __restrict__ bhf,
    const float* __restrict__ bhg, const float* __restrict__ bho,
    const float* __restrict__ bpe,
    const float* __restrict__ Wii, const float* __restrict__ Wif,
    const float* __restrict__ Wig, const float* __restrict__ Wio,
    const float* __restrict__ Wse, const float* __restrict__ Wout,
    float* __restrict__ dinv, float* __restrict__ bcat,
    unsigned short* __restrict__ WseP, unsigned short* __restrict__ WxeP,
    unsigned short* __restrict__ WoutP, int* __restrict__ cnt) {
  const int blk = blockIdx.x, t = threadIdx.x;
  if (blk < 1024) {                       // dinv: wave per row
    int row = blk * 4 + (t >> 6);
    int lane = t & 63;
    const float* a = A + (size_t)row * N_;
    float s = 0.f;
    for (int j = lane; j < N_; j += 64) s += a[j];
    #pragma unroll
    for (int off = 32; off > 0; off >>= 1) s += __shfl_down(s, off);
    if (lane == 0) dinv[row] = (s > 0.f) ? rsqrtf(s) : 0.f;
  } else if (blk < 1026) {                // bcat
    int col = (blk - 1024) * 256 + t;
    int g = col >> 7, j = col & 127;
    const float* bx = (g == 0) ? bii : (g == 1) ? bif : (g == 2) ? big : bio;
    const float* bh = (g == 0) ? bhi : (g == 1) ? bhf : (g == 2) ? bhg : bho;
    const float* Wx = (g == 0) ? Wii : (g == 1) ? Wif : (g == 2) ? Wig : Wio;
    float s = bx[j] + bh[j];
    for (int k = 0; k < NE_; k++) s += bpe[k] * Wx[(size_t)(128 + k) * NH_ + j];
    bcat[col] = s;
  } else if (blk < 1346) {                // pack WseP / WxeP / WoutP
    int idx = (blk - 1026) * 256 + t;     // < 81920
    if (idx < 8192) {
      int k = idx >> 7, c = idx & 127;
      WseP[((size_t)(k >> 3) * 128 + c) * 8 + (k & 7)] = f2b(Wse[(size_t)k * 128 + c]);
    } else if (idx < 8192 + 65536) {
      int i = idx - 8192;
      int k = i >> 9, col = i & 511, g = col >> 7, j = col & 127;
      const float* Wx = (g == 0) ? Wii : (g == 1) ? Wif : (g == 2) ? Wig : Wio;
      WxeP[((size_t)(k >> 3) * 512 + col) * 8 + (k & 7)] = f2b(Wx[(size_t)k * 128 + j]);
    } else if (idx < 8192 + 65536 + 8192) {
      int i = idx - 8192 - 65536;
      int k = i >> 6, c = i & 63;
      WoutP[((size_t)(k >> 3) * 64 + c) * 8 + (k & 7)] = f2b(Wout[(size_t)k * 64 + c]);
    }
  } else {                                // zero sync counters
    if (t < 128) cnt[t] = 0;
  }
}

// ---------------- fused setup kernel 2: WUP2 (WC dot inlined) ------------
__global__ __launch_bounds__(256) void k_setup2(
    const float* __restrict__ Wpe,
    const float* __restrict__ Whi, const float* __restrict__ Whf,
    const float* __restrict__ Whg, const float* __restrict__ Who,
    const float* __restrict__ Wii, const float* __restrict__ Wif,
    const float* __restrict__ Wig, const float* __restrict__ Wio,
    unsigned short* __restrict__ WUP2) {
  int idx = blockIdx.x * 256 + threadIdx.x;    // 131072
  int k = idx >> 9, col = idx & 511, g = col >> 7, j = col & 127;
  float v;
  if (k < 128) {
    const float* Wx = (g == 0) ? Wii : (g == 1) ? Wif : (g == 2) ? Wig : Wio;
    float s = 0.f;
    for (int mm = 0; mm < 128; mm++)
      s += Wpe[(size_t)k * 128 + mm] * Wx[(size_t)(128 + mm) * 128 + j];
    v = s;
  } else {
    const float* Wh = (g == 0) ? Whi : (g == 1) ? Whf : (g == 2) ? Whg : Who;
    v = Wh[(size_t)(k - 128) * 128 + j];
  }
  WUP2[((size_t)(k >> 3) * 512 + col) * 8 + (k & 7)] = f2b(v);
}

// ---------------- persistent fused kernel ----------------
// 256 blocks x 512 threads (8 waves/CU); batch b = blockIdx&7 (XCD-affine),
// row-tile rt = blockIdx>>3; block owns rows r0=b*512+rt*16 .. +15.
// Wave w owns h-cols c=16w+m; computes ALL 4 gates for those cols, so the
// LSTM cell is lane-private (no LDS gate exchange). Z-weights pinned in
// VGPR/AGPR (wz: 8kc x 4gate x 16B = 128 regs/lane).
// Cross-block h exchange: sc0sc1 write-through stores / read-through loads
// via L3; monotone per-batch counters with RELAXED system-scope atomics.
__global__ __launch_bounds__(512, 2) void k_persist(
    const float* __restrict__ A, const float* __restrict__ dinv,
    const float* __restrict__ X,
    const unsigned short* __restrict__ WseP, const float* __restrict__ bse,
    const unsigned short* __restrict__ WxeP, const float* __restrict__ bcat,
    const unsigned short* __restrict__ WUP2,
    const unsigned short* __restrict__ WoutP, const float* __restrict__ bout,
    unsigned short* __restrict__ hP,   // [2][8][64*128*8]
    int* __restrict__ cnt,             // [8*16]
    float* __restrict__ out) {
  __shared__ __align__(16) unsigned short as[16][520];   // scaled A rows, bf16
  __shared__ __align__(16) unsigned short xh[16][264];   // [G | h_own] bf16
  __shared__ __align__(16) float ps[1536];               // prologue scratch

  const int t = threadIdx.x;
  const int b = blockIdx.x & 7;         // batch -> XCD-affine
  const int rt = blockIdx.x >> 3;       // row tile within batch
  const int r0 = b * N_ + rt * 16;      // global row base
  const int l = t & 63, w = t >> 6, m = l & 15, kg = l >> 4;
  const int c = w * 16 + m;             // owned h/G column

  float* X0s = ps;          // 1024 floats
  float* dvb = ps + 1024;   // 512 floats

  // ---- prologue ----
  if (t < 512) dvb[t] = dinv[b * 512 + t];
  for (int i = t; i < 1024; i += 512) {
    int r = i >> 6, cc = i & 63;
    float v = X[((size_t)(r0 + r) * T_) * NIN_ + cc];
    X0s[i] = v;
    out[((size_t)(r0 + r) * T_) * NIN_ + cc] = v;   // out[:, t=0] = X0
  }
  __syncthreads();
  for (int i = t; i < 1024; i += 512) xh[i >> 6][i & 63] = f2b(X0s[i]);
  for (int i = t; i < 8192; i += 512) {
    int r = i >> 9, k = i & 511;
    as[r][k] = f2b(A[(size_t)(r0 + r) * 512 + k] * dinv[r0 + r] * dvb[k]);
  }
  __syncthreads();
  // es = X0 @ WseP + bse -> bf16 -> xh[:,128:256]; wave w: cols c
  {
    f4_t e;
    float bv = bse[c];
    #pragma unroll
    for (int r = 0; r < 4; r++) e[r] = bv;
    #pragma unroll
    for (int kc = 0; kc < 2; kc++) {
      s8_t a = *(const s8_t*)&xh[m][kc * 32 + kg * 8];
      s8_t bf = *(const s8_t*)&WseP[((size_t)(kc * 4 + kg) * 128 + c) * 8];
      e = __builtin_amdgcn_mfma_f32_16x16x32_bf16(a, bf, e, 0, 0, 0);
    }
    #pragma unroll
    for (int r = 0; r < 4; r++)
      xh[kg * 4 + r][128 + c] = f2b(e[r]);
  }
  __syncthreads();
  // espre in registers: esr[g] = (es @ WxeP + bcat) for col g*128+c
  f4_t esr[4];
  #pragma unroll
  for (int g = 0; g < 4; g++) {
    float bv = bcat[g * 128 + c];
    #pragma unroll
    for (int r = 0; r < 4; r++) esr[g][r] = bv;
  }
  #pragma unroll
  for (int kc = 0; kc < 4; kc++) {
    s8_t a = *(const s8_t*)&xh[m][128 + kc * 32 + kg * 8];
    #pragma unroll
    for (int g = 0; g < 4; g++) {
      s8_t bf = *(const s8_t*)&WxeP[((size_t)(kc * 4 + kg) * 512 + g * 128 + c) * 8];
      esr[g] = __builtin_amdgcn_mfma_f32_16x16x32_bf16(a, bf, esr[g], 0, 0, 0);
    }
  }
  // persistent per-thread state
  f4_t oacc = {0.f, 0.f, 0.f, 0.f};
  float bo = 0.f;
  if (w < 4) {
    bo = bout[w * 16 + m];
    #pragma unroll
    for (int r = 0; r < 4; r++) oacc[r] = X0s[(kg * 4 + r) * 64 + w * 16 + m];
  }
  float cs[4] = {0.f, 0.f, 0.f, 0.f};   // c-state: rows kg*4+r, col c
  // pin Z-GEMM weights in registers (512 B/lane)
  s8_t wz[8][4];
  #pragma unroll
  for (int kc = 0; kc < 8; kc++)
    #pragma unroll
    for (int g = 0; g < 4; g++)
      wz[kc][g] = *(const s8_t*)&WUP2[((size_t)(kc * 4 + kg) * 512 + g * 128 + c) * 8];
  __syncthreads();
  for (int i = t; i < 16 * 264; i += 512) ((unsigned short*)xh)[i] = 0;
  __syncthreads();

  // ---- main loop over timesteps ----
  for (int tt = 1; tt < T_; tt++) {
    if (tt > 1) {
      // per-wave poll: wait for all 32 blocks of batch to publish h^{tt-1}
      const int need = 32 * (tt - 1);
      while (__hip_atomic_load(cnt + b * 16, __ATOMIC_RELAXED,
                               __HIP_MEMORY_SCOPE_SYSTEM) < need)
        __builtin_amdgcn_s_sleep(1);
      // graph GEMM: G(own rows, col c), K=512, B-frags read-through from L3
      const unsigned short* hPb =
          hP + ((size_t)((tt - 1) & 1) * 8 + b) * 65536;
      i4_t hf[16];
      #pragma unroll
      for (int kc = 0; kc < 16; kc++)
        hf[kc] = load_coherent16(&hPb[((size_t)(kc * 4 + kg) * 128 + c) * 8]);
      f4_t ga = {0.f, 0.f, 0.f, 0.f};
      asm volatile("s_waitcnt vmcnt(8)"
                   : "+v"(hf[0]), "+v"(hf[1]), "+v"(hf[2]), "+v"(hf[3]),
                     "+v"(hf[4]), "+v"(hf[5]), "+v"(hf[6]), "+v"(hf[7])
                   :: "memory");
      #pragma unroll
      for (int kc = 0; kc < 8; kc++) {
        s8_t a = *(const s8_t*)&as[m][kc * 32 + kg * 8];
        ga = __builtin_amdgcn_mfma_f32_16x16x32_bf16(a, *(const s8_t*)&hf[kc],
                                                     ga, 0, 0, 0);
      }
      asm volatile("s_waitcnt vmcnt(0)"
                   : "+v"(hf[8]), "+v"(hf[9]), "+v"(hf[10]), "+v"(hf[11]),
                     "+v"(hf[12]), "+v"(hf[13]), "+v"(hf[14]), "+v"(hf[15])
                   :: "memory");
      #pragma unroll
      for (int kc = 8; kc < 16; kc++) {
        s8_t a = *(const s8_t*)&as[m][kc * 32 + kg * 8];
        ga = __builtin_amdgcn_mfma_f32_16x16x32_bf16(a, *(const s8_t*)&hf[kc],
                                                     ga, 0, 0, 0);
      }
      #pragma unroll
      for (int r = 0; r < 4; r++)
        xh[kg * 4 + r][c] = f2b(ga[r]);
      __syncthreads();   // B1: G visible before Z reads
    }
    // Z-GEMM: acc[g] = espre + [G|h] @ wz  (weights in registers)
    f4_t acc[4];
    #pragma unroll
    for (int g = 0; g < 4; g++) acc[g] = esr[g];
    #pragma unroll
    for (int kc = 0; kc < 8; kc++) {
      s8_t a = *(const s8_t*)&xh[m][kc * 32 + kg * 8];
      #pragma unroll
      for (int g = 0; g < 4; g++)
        acc[g] = __builtin_amdgcn_mfma_f32_16x16x32_bf16(a, wz[kc][g], acc[g], 0, 0, 0);
    }
    // lane-private cell update: rows kg*4+r, col c
    union { unsigned short u[4]; i2_t v; } hb;
    #pragma unroll
    for (int r = 0; r < 4; r++) {
      float it = sigm(acc[0][r]), ft = sigm(acc[1][r]);
      float gt = tanh_fast(acc[2][r]), ot = sigm(acc[3][r]);
      cs[r] = ft * cs[r] + it * gt;
      hb.u[r] = f2b(ot * tanh_fast(cs[r]));
    }
    // publish h directly from registers (1 coherent dwordx2 per lane)
    if (tt < T_ - 1) {
      unsigned short* dst = hP + ((size_t)(tt & 1) * 8 + b) * 65536 +
                            (size_t)(rt * 2 + (kg >> 1)) * 1024 +
                            (size_t)c * 8 + (kg & 1) * 4;
      store_coherent8(dst, hb.v);
    }
    __syncthreads();   // B2: all Z xh-reads done before h overwrite
    #pragma unroll
    for (int r = 0; r < 4; r++)
      xh[kg * 4 + r][128 + c] = hb.u[r];
    if (tt < T_ - 1) wait_vm0();   // own publish store drained to L3
    __syncthreads();   // B3: h(t) visible in xh; all publishes drained
    if (tt < T_ - 1 && t == 0)
      __hip_atomic_fetch_add(cnt + b * 16, 1, __ATOMIC_RELAXED,
                             __HIP_MEMORY_SCOPE_SYSTEM);
    // out GEMM (waves 0..3): oacc += h @ WoutP + bout ; store out[:, tt]
    if (w < 4) {
      f4_t o = {0.f, 0.f, 0.f, 0.f};
      #pragma unroll
      for (int kc = 0; kc < 4; kc++) {
        s8_t a = *(const s8_t*)&xh[m][128 + kc * 32 + kg * 8];
        s8_t bf = *(const s8_t*)&WoutP[((size_t)(kc * 4 + kg) * 64 + w * 16 + m) * 8];
        o = __builtin_amdgcn_mfma_f32_16x16x32_bf16(a, bf, o, 0, 0, 0);
      }
      #pragma unroll
      for (int r = 0; r < 4; r++) {
        oacc[r] += o[r] + bo;
        out[((size_t)(r0 + kg * 4 + r) * T_ + tt) * NIN_ + w * 16 + m] = oacc[r];
      }
    }
  }
}

extern "C" void kernel_launch(void* const* d_in, const int* in_sizes, int n_in,
                              void* d_out, int out_size, void* d_ws, size_t ws_size,
                              hipStream_t stream) {
  const float* X    = (const float*)d_in[0];
  const float* A    = (const float*)d_in[1];
  const float* Wse  = (const float*)d_in[2];
  const float* bse  = (const float*)d_in[3];
  const float* Wpe  = (const float*)d_in[4];
  const float* bpe  = (const float*)d_in[5];
  const float* Wii  = (const float*)d_in[6];
  const float* bii  = (const float*)d_in[7];
  const float* Whi  = (const float*)d_in[8];
  const float* bhi  = (const float*)d_in[9];
  const float* Wif  = (const float*)d_in[10];
  const float* bif_ = (const float*)d_in[11];
  const float* Whf  = (const float*)d_in[12];
  const float* bhf  = (const float*)d_in[13];
  const float* Wig  = (const float*)d_in[14];
  const float* big_ = (const float*)d_in[15];
  const float* Whg  = (const float*)d_in[16];
  const float* bhg  = (const float*)d_in[17];
  const float* Wio  = (const float*)d_in[18];
  const float* bio  = (const float*)d_in[19];
  const float* Who  = (const float*)d_in[20];
  const float* bho  = (const float*)d_in[21];
  const float* Wout = (const float*)d_in[22];
  const float* bout = (const float*)d_in[23];
  float* out = (float*)d_out;
  char* ws = (char*)d_ws;

  size_t off = 0;
  float* dinv = (float*)(ws + off);                    off += 4096 * 4;
  float* bcat = (float*)(ws + off);                    off += 512 * 4;
  unsigned short* WUP2  = (unsigned short*)(ws + off); off += 131072 * 2;
  unsigned short* WseP  = (unsigned short*)(ws + off); off += 8192 * 2;
  unsigned short* WxeP  = (unsigned short*)(ws + off); off += 65536 * 2;
  unsigned short* WoutP = (unsigned short*)(ws + off); off += 8192 * 2;
  unsigned short* hP    = (unsigned short*)(ws + off); off += (size_t)2 * 8 * 65536 * 2;
  int* cnt = (int*)(ws + off);                         off += 128 * 4;

  k_setup1<<<1347, 256, 0, stream>>>(A, bii, bif_, big_, bio, bhi, bhf, bhg,
                                     bho, bpe, Wii, Wif, Wig, Wio, Wse, Wout,
                                     dinv, bcat, WseP, WxeP, WoutP, cnt);
  k_setup2<<<512, 256, 0, stream>>>(Wpe, Whi, Whf, Whg, Who,
                                    Wii, Wif, Wig, Wio, WUP2);

  void* args[] = {(void*)&A, (void*)&dinv, (void*)&X,
                  (void*)&WseP, (void*)&bse, (void*)&WxeP, (void*)&bcat,
                  (void*)&WUP2, (void*)&WoutP, (void*)&bout,
                  (void*)&hP, (void*)&cnt, (void*)&out};
  if (hipLaunchCooperativeKernel((const void*)k_persist, dim3(256), dim3(512),
                                 args, 0, stream) != hipSuccess) {
    // fallback: plain launch; grid == CU count with 1 block/CU co-resides
    k_persist<<<256, 512, 0, stream>>>(A, dinv, X, WseP, bse, WxeP, bcat,
                                       WUP2, WoutP, bout, hP, cnt, out);
  }
}

// Round 7
// 539.789 us; speedup vs baseline: 4.3154x; 1.1069x over previous
//
#include <hip/hip_runtime.h>
#include <math.h>

#define B_ 8
#define N_ 512
#define T_ 64
#define NIN_ 64
#define NE_ 128
#define NH_ 128
#define NR_ 4096   // B*N

typedef __attribute__((ext_vector_type(8))) short s8_t;   // 8 bf16 = 16B
typedef __attribute__((ext_vector_type(4))) short s4_t;   // 4 bf16 = 8B
typedef __attribute__((ext_vector_type(4))) float f4_t;
typedef __attribute__((ext_vector_type(4))) int i4_t;
typedef __attribute__((ext_vector_type(2))) int i2_t;

__device__ __forceinline__ float sigm(float x) {
  x = fminf(fmaxf(x, -30.f), 30.f);
  return 1.f / (1.f + __expf(-x));
}
__device__ __forceinline__ float tanh_fast(float x) {
  x = fminf(fmaxf(x, -15.f), 15.f);
  float e = __expf(2.f * x);
  return (e - 1.f) / (e + 1.f);
}
__device__ __forceinline__ unsigned short f2b(float f) {
  union { float f; unsigned u; } v; v.f = f;
  unsigned r = (v.u + 0x7FFFu + ((v.u >> 16) & 1u)) >> 16;
  return (unsigned short)r;
}

// coherent (cache-state-neutral) accesses via L3 — no cache maintenance
__device__ __forceinline__ i4_t load_coherent16(const void* p) {
  i4_t r;
  asm volatile("global_load_dwordx4 %0, %1, off sc0 sc1"
               : "=v"(r) : "v"(p) : "memory");
  return r;
}
__device__ __forceinline__ void store_coherent8(void* p, i2_t v) {
  asm volatile("global_store_dwordx2 %0, %1, off sc0 sc1"
               :: "v"(p), "v"(v) : "memory");
}
__device__ __forceinline__ void wait_vm0() {
  asm volatile("s_waitcnt vmcnt(0)" ::: "memory");
}

// ---------------- fused setup kernel 1: dinv + bcat + pack_misc + cnt ----
__global__ __launch_bounds__(256) void k_setup1(
    const float* __restrict__ A,
    const float* __restrict__ bii, const float* __restrict__ bif,
    const float* __restrict__ big, const float* __restrict__ bio,
    const float* __restrict__ bhi, const float* __restrict__ bhf,
    const float* __restrict__ bhg, const float* __restrict__ bho,
    const float* __restrict__ bpe,
    const float* __restrict__ Wii, const float* __restrict__ Wif,
    const float* __restrict__ Wig, const float* __restrict__ Wio,
    const float* __restrict__ Wse, const float* __restrict__ Wout,
    float* __restrict__ dinv, float* __restrict__ bcat,
    unsigned short* __restrict__ WseP, unsigned short* __restrict__ WxeP,
    unsigned short* __restrict__ WoutP, int* __restrict__ cnt) {
  const int blk = blockIdx.x, t = threadIdx.x;
  if (blk < 1024) {                       // dinv: wave per row
    int row = blk * 4 + (t >> 6);
    int lane = t & 63;
    const float* a = A + (size_t)row * N_;
    float s = 0.f;
    for (int j = lane; j < N_; j += 64) s += a[j];
    #pragma unroll
    for (int off = 32; off > 0; off >>= 1) s += __shfl_down(s, off);
    if (lane == 0) dinv[row] = (s > 0.f) ? rsqrtf(s) : 0.f;
  } else if (blk < 1026) {                // bcat
    int col = (blk - 1024) * 256 + t;
    int g = col >> 7, j = col & 127;
    const float* bx = (g == 0) ? bii : (g == 1) ? bif : (g == 2) ? big : bio;
    const float* bh = (g == 0) ? bhi : (g == 1) ? bhf : (g == 2) ? bhg : bho;
    const float* Wx = (g == 0) ? Wii : (g == 1) ? Wif : (g == 2) ? Wig : Wio;
    float s = bx[j] + bh[j];
    for (int k = 0; k < NE_; k++) s += bpe[k] * Wx[(size_t)(128 + k) * NH_ + j];
    bcat[col] = s;
  } else if (blk < 1346) {                // pack WseP / WxeP / WoutP
    int idx = (blk - 1026) * 256 + t;     // < 81920
    if (idx < 8192) {
      int k = idx >> 7, c = idx & 127;
      WseP[((size_t)(k >> 3) * 128 + c) * 8 + (k & 7)] = f2b(Wse[(size_t)k * 128 + c]);
    } else if (idx < 8192 + 65536) {
      int i = idx - 8192;
      int k = i >> 9, col = i & 511, g = col >> 7, j = col & 127;
      const float* Wx = (g == 0) ? Wii : (g == 1) ? Wif : (g == 2) ? Wig : Wio;
      WxeP[((size_t)(k >> 3) * 512 + col) * 8 + (k & 7)] = f2b(Wx[(size_t)k * 128 + j]);
    } else if (idx < 8192 + 65536 + 8192) {
      int i = idx - 8192 - 65536;
      int k = i >> 6, c = i & 63;
      WoutP[((size_t)(k >> 3) * 64 + c) * 8 + (k & 7)] = f2b(Wout[(size_t)k * 64 + c]);
    }
  } else {                                // zero sync counters
    if (t < 128) cnt[t] = 0;
  }
}

// ---------------- fused setup kernel 2: WUP2 (WC dot inlined) ------------
__global__ __launch_bounds__(256) void k_setup2(
    const float* __restrict__ Wpe,
    const float* __restrict__ Whi, const float* __restrict__ Whf,
    const float* __restrict__ Whg, const float* __restrict__ Who,
    const float* __restrict__ Wii, const float* __restrict__ Wif,
    const float* __restrict__ Wig, const float* __restrict__ Wio,
    unsigned short* __restrict__ WUP2) {
  int idx = blockIdx.x * 256 + threadIdx.x;    // 131072
  int k = idx >> 9, col = idx & 511, g = col >> 7, j = col & 127;
  float v;
  if (k < 128) {
    const float* Wx = (g == 0) ? Wii : (g == 1) ? Wif : (g == 2) ? Wig : Wio;
    float s = 0.f;
    for (int mm = 0; mm < 128; mm++)
      s += Wpe[(size_t)k * 128 + mm] * Wx[(size_t)(128 + mm) * 128 + j];
    v = s;
  } else {
    const float* Wh = (g == 0) ? Whi : (g == 1) ? Whf : (g == 2) ? Whg : Who;
    v = Wh[(size_t)(k - 128) * 128 + j];
  }
  WUP2[((size_t)(k >> 3) * 512 + col) * 8 + (k & 7)] = f2b(v);
}

// ---------------- persistent fused kernel ----------------
// 256 blocks x 512 threads; batch b = blockIdx&7 (XCD-affine), rt = blk>>3.
// Wave w owns h-cols c=16w+m, all 4 gates -> lane-private LSTM cell.
// Z-weights pinned in regs (wz: 8x4x16B = 128 regs/lane).
// h exchange: write-through sc0sc1 stores (data at L3 before counter bump).
// fresh==true: per-step FRESH hP buffers -> consumers use PLAIN cached loads
// (address never cached before => no staleness; same-XCD peers hit L2).
// fresh==false: R6 fallback (2 buffers + sc0sc1 coherent loads).
__global__ __launch_bounds__(512, 2) void k_persist(
    const float* __restrict__ A, const float* __restrict__ dinv,
    const float* __restrict__ X,
    const unsigned short* __restrict__ WseP, const float* __restrict__ bse,
    const unsigned short* __restrict__ WxeP, const float* __restrict__ bcat,
    const unsigned short* __restrict__ WUP2,
    const unsigned short* __restrict__ WoutP, const float* __restrict__ bout,
    unsigned short* __restrict__ hP,   // [nbuf][8][64*128*8]
    int* __restrict__ cnt,             // [8*16]
    float* __restrict__ out, int fresh) {
  __shared__ __align__(16) unsigned short as[16][520];   // scaled A rows, bf16
  __shared__ __align__(16) unsigned short xh[16][392];   // [G | h0 | h1] bf16
  __shared__ __align__(16) float ps[1536];               // prologue scratch

  const int t = threadIdx.x;
  const int b = blockIdx.x & 7;         // batch -> XCD-affine
  const int rt = blockIdx.x >> 3;       // row tile within batch
  const int r0 = b * N_ + rt * 16;      // global row base
  const int l = t & 63, w = t >> 6, m = l & 15, kg = l >> 4;
  const int c = w * 16 + m;             // owned h/G column

  float* X0s = ps;          // 1024 floats
  float* dvb = ps + 1024;   // 512 floats

  // ---- prologue ----
  if (t < 512) dvb[t] = dinv[b * 512 + t];
  for (int i = t; i < 1024; i += 512) {
    int r = i >> 6, cc = i & 63;
    float v = X[((size_t)(r0 + r) * T_) * NIN_ + cc];
    X0s[i] = v;
    out[((size_t)(r0 + r) * T_) * NIN_ + cc] = v;   // out[:, t=0] = X0
  }
  __syncthreads();
  for (int i = t; i < 1024; i += 512) xh[i >> 6][i & 63] = f2b(X0s[i]);
  for (int i = t; i < 8192; i += 512) {
    int r = i >> 9, k = i & 511;
    as[r][k] = f2b(A[(size_t)(r0 + r) * 512 + k] * dinv[r0 + r] * dvb[k]);
  }
  __syncthreads();
  // es = X0 @ WseP + bse -> bf16 -> xh[:,128:256] (slot0 scratch)
  {
    f4_t e;
    float bv = bse[c];
    #pragma unroll
    for (int r = 0; r < 4; r++) e[r] = bv;
    #pragma unroll
    for (int kc = 0; kc < 2; kc++) {
      s8_t a = *(const s8_t*)&xh[m][kc * 32 + kg * 8];
      s8_t bf = *(const s8_t*)&WseP[((size_t)(kc * 4 + kg) * 128 + c) * 8];
      e = __builtin_amdgcn_mfma_f32_16x16x32_bf16(a, bf, e, 0, 0, 0);
    }
    #pragma unroll
    for (int r = 0; r < 4; r++)
      xh[kg * 4 + r][128 + c] = f2b(e[r]);
  }
  __syncthreads();
  // espre in registers: esr[g] = (es @ WxeP + bcat) for col g*128+c
  f4_t esr[4];
  #pragma unroll
  for (int g = 0; g < 4; g++) {
    float bv = bcat[g * 128 + c];
    #pragma unroll
    for (int r = 0; r < 4; r++) esr[g][r] = bv;
  }
  #pragma unroll
  for (int kc = 0; kc < 4; kc++) {
    s8_t a = *(const s8_t*)&xh[m][128 + kc * 32 + kg * 8];
    #pragma unroll
    for (int g = 0; g < 4; g++) {
      s8_t bf = *(const s8_t*)&WxeP[((size_t)(kc * 4 + kg) * 512 + g * 128 + c) * 8];
      esr[g] = __builtin_amdgcn_mfma_f32_16x16x32_bf16(a, bf, esr[g], 0, 0, 0);
    }
  }
  // persistent per-thread state
  f4_t oacc = {0.f, 0.f, 0.f, 0.f};
  float bo = 0.f;
  if (w < 4) {
    bo = bout[w * 16 + m];
    #pragma unroll
    for (int r = 0; r < 4; r++) oacc[r] = X0s[(kg * 4 + r) * 64 + w * 16 + m];
  }
  float cs[4] = {0.f, 0.f, 0.f, 0.f};   // c-state: rows kg*4+r, col c
  // pin Z-GEMM weights in registers (512 B/lane)
  s8_t wz[8][4];
  #pragma unroll
  for (int kc = 0; kc < 8; kc++)
    #pragma unroll
    for (int g = 0; g < 4; g++)
      wz[kc][g] = *(const s8_t*)&WUP2[((size_t)(kc * 4 + kg) * 512 + g * 128 + c) * 8];
  __syncthreads();
  // zero G region + h slot0 (h(0)=0); slot1 fully overwritten at tt=1
  for (int i = t; i < 16 * 256; i += 512) {
    int r = i >> 8, cc = i & 255;
    xh[r][cc] = 0;
  }
  __syncthreads();

  // ---- main loop over timesteps ----
  for (int tt = 1; tt < T_; tt++) {
    const int hoff_old = 128 + ((tt - 1) & 1) * 128;
    const int hoff_new = 128 + (tt & 1) * 128;
    if (tt > 1) {
      // single poller (lane 511), backoff; others wait at barrier
      if (t == 511) {
        const int need = 32 * (tt - 1);
        while (__hip_atomic_load(cnt + b * 16, __ATOMIC_RELAXED,
                                 __HIP_MEMORY_SCOPE_SYSTEM) < need)
          __builtin_amdgcn_s_sleep(4);
      }
      __syncthreads();
      asm volatile("" ::: "memory");   // no load hoisting above the handshake
      // graph GEMM: G(own rows, col c), K=512
      const int bi = fresh ? (tt - 2) : ((tt - 1) & 1);
      const unsigned short* hPb = hP + ((size_t)bi * 8 + b) * 65536;
      i4_t hf[16];
      if (fresh) {
        #pragma unroll
        for (int kc = 0; kc < 16; kc++)
          hf[kc] = *(const i4_t*)&hPb[((size_t)(kc * 4 + kg) * 128 + c) * 8];
      } else {
        #pragma unroll
        for (int kc = 0; kc < 16; kc++)
          hf[kc] = load_coherent16(&hPb[((size_t)(kc * 4 + kg) * 128 + c) * 8]);
        wait_vm0();
      }
      f4_t ga = {0.f, 0.f, 0.f, 0.f};
      #pragma unroll
      for (int kc = 0; kc < 16; kc++) {
        s8_t a = *(const s8_t*)&as[m][kc * 32 + kg * 8];
        ga = __builtin_amdgcn_mfma_f32_16x16x32_bf16(a, *(const s8_t*)&hf[kc],
                                                     ga, 0, 0, 0);
      }
      #pragma unroll
      for (int r = 0; r < 4; r++)
        xh[kg * 4 + r][c] = f2b(ga[r]);
      __syncthreads();   // B1: G visible before Z reads
    }
    // Z-GEMM: acc[g] = espre + [G|h_old] @ wz (weights in registers)
    f4_t acc[4];
    #pragma unroll
    for (int g = 0; g < 4; g++) acc[g] = esr[g];
    #pragma unroll
    for (int kc = 0; kc < 8; kc++) {
      const int koff = (kc < 4) ? kc * 32 : hoff_old + (kc - 4) * 32;
      s8_t a = *(const s8_t*)&xh[m][koff + kg * 8];
      #pragma unroll
      for (int g = 0; g < 4; g++)
        acc[g] = __builtin_amdgcn_mfma_f32_16x16x32_bf16(a, wz[kc][g], acc[g], 0, 0, 0);
    }
    // lane-private cell update: rows kg*4+r, col c
    union { unsigned short u[4]; i2_t v; } hb;
    #pragma unroll
    for (int r = 0; r < 4; r++) {
      float it = sigm(acc[0][r]), ft = sigm(acc[1][r]);
      float gt = tanh_fast(acc[2][r]), ot = sigm(acc[3][r]);
      cs[r] = ft * cs[r] + it * gt;
      hb.u[r] = f2b(ot * tanh_fast(cs[r]));
    }
    // h_new into the other LDS slot (no barrier needed: disjoint region)
    #pragma unroll
    for (int r = 0; r < 4; r++)
      xh[kg * 4 + r][hoff_new + c] = hb.u[r];
    // publish h from regs: write-through to L3
    if (tt < T_ - 1) {
      const int bo_ = fresh ? (tt - 1) : (tt & 1);
      unsigned short* dst = hP + ((size_t)bo_ * 8 + b) * 65536 +
                            (size_t)(rt * 2 + (kg >> 1)) * 1024 +
                            (size_t)c * 8 + (kg & 1) * 4;
      store_coherent8(dst, hb.v);
      wait_vm0();   // own publish drained to L3
    }
    __syncthreads();   // B2: h_new visible in xh; all publishes drained
    if (tt < T_ - 1 && t == 0)
      __hip_atomic_fetch_add(cnt + b * 16, 1, __ATOMIC_RELAXED,
                             __HIP_MEMORY_SCOPE_SYSTEM);
    // out GEMM (waves 0..3): oacc += h @ WoutP + bout ; store out[:, tt]
    if (w < 4) {
      f4_t o = {0.f, 0.f, 0.f, 0.f};
      #pragma unroll
      for (int kc = 0; kc < 4; kc++) {
        s8_t a = *(const s8_t*)&xh[m][hoff_new + kc * 32 + kg * 8];
        s8_t bf = *(const s8_t*)&WoutP[((size_t)(kc * 4 + kg) * 64 + w * 16 + m) * 8];
        o = __builtin_amdgcn_mfma_f32_16x16x32_bf16(a, bf, o, 0, 0, 0);
      }
      #pragma unroll
      for (int r = 0; r < 4; r++) {
        oacc[r] += o[r] + bo;
        out[((size_t)(r0 + kg * 4 + r) * T_ + tt) * NIN_ + w * 16 + m] = oacc[r];
      }
    }
  }
}

extern "C" void kernel_launch(void* const* d_in, const int* in_sizes, int n_in,
                              void* d_out, int out_size, void* d_ws, size_t ws_size,
                              hipStream_t stream) {
  const float* X    = (const float*)d_in[0];
  const float* A    = (const float*)d_in[1];
  const float* Wse  = (const float*)d_in[2];
  const float* bse  = (const float*)d_in[3];
  const float* Wpe  = (const float*)d_in[4];
  const float* bpe  = (const float*)d_in[5];
  const float* Wii  = (const float*)d_in[6];
  const float* bii  = (const float*)d_in[7];
  const float* Whi  = (const float*)d_in[8];
  const float* bhi  = (const float*)d_in[9];
  const float* Wif  = (const float*)d_in[10];
  const float* bif_ = (const float*)d_in[11];
  const float* Whf  = (const float*)d_in[12];
  const float* bhf  = (const float*)d_in[13];
  const float* Wig  = (const float*)d_in[14];
  const float* big_ = (const float*)d_in[15];
  const float* Whg  = (const float*)d_in[16];
  const float* bhg  = (const float*)d_in[17];
  const float* Wio  = (const float*)d_in[18];
  const float* bio  = (const float*)d_in[19];
  const float* Who  = (const float*)d_in[20];
  const float* bho  = (const float*)d_in[21];
  const float* Wout = (const float*)d_in[22];
  const float* bout = (const float*)d_in[23];
  float* out = (float*)d_out;
  char* ws = (char*)d_ws;

  size_t off = 0;
  float* dinv = (float*)(ws + off);                    off += 4096 * 4;
  float* bcat = (float*)(ws + off);                    off += 512 * 4;
  unsigned short* WUP2  = (unsigned short*)(ws + off); off += 131072 * 2;
  unsigned short* WseP  = (unsigned short*)(ws + off); off += 8192 * 2;
  unsigned short* WxeP  = (unsigned short*)(ws + off); off += 65536 * 2;
  unsigned short* WoutP = (unsigned short*)(ws + off); off += 8192 * 2;
  int* cnt = (int*)(ws + off);                         off += 128 * 4;
  unsigned short* hP    = (unsigned short*)(ws + off);
  // fresh path: one 128KB buffer per batch per step (62 steps published)
  const size_t fresh_bytes = (size_t)62 * 8 * 65536 * 2;
  int fresh = (ws_size >= off + fresh_bytes) ? 1 : 0;

  k_setup1<<<1347, 256, 0, stream>>>(A, bii, bif_, big_, bio, bhi, bhf, bhg,
                                     bho, bpe, Wii, Wif, Wig, Wio, Wse, Wout,
                                     dinv, bcat, WseP, WxeP, WoutP, cnt);
  k_setup2<<<512, 256, 0, stream>>>(Wpe, Whi, Whf, Whg, Who,
                                    Wii, Wif, Wig, Wio, WUP2);

  void* args[] = {(void*)&A, (void*)&dinv, (void*)&X,
                  (void*)&WseP, (void*)&bse, (void*)&WxeP, (void*)&bcat,
                  (void*)&WUP2, (void*)&WoutP, (void*)&bout,
                  (void*)&hP, (void*)&cnt, (void*)&out, (void*)&fresh};
  if (hipLaunchCooperativeKernel((const void*)k_persist, dim3(256), dim3(512),
                                 args, 0, stream) != hipSuccess) {
    // fallback: plain launch; grid == CU count with 1 block/CU co-resides
    k_persist<<<256, 512, 0, stream>>>(A, dinv, X, WseP, bse, WxeP, bcat,
                                       WUP2, WoutP, bout, hP, cnt, out, fresh);
  }
}